// Round 16
// baseline (1127.107 us; speedup 1.0000x reference)
//
#include <hip/hip_runtime.h>

#define BB   2048
#define NNX  64
#define DD   256
#define KKC  32
#define LLN  2
#define HHN  8
#define DHH  32
#define DFFN 1024
#define BNT  (BB*NNX)   // 131072

typedef short s16x8 __attribute__((ext_vector_type(8)));
typedef float f32x4 __attribute__((ext_vector_type(4)));

#define GLOAD_LDS16(gp, lp) __builtin_amdgcn_global_load_lds( \
    (const __attribute__((address_space(1))) void*)(gp),      \
    (__attribute__((address_space(3))) void*)(lp), 16, 0, 0)

#define WAITVM4() asm volatile("s_waitcnt vmcnt(4)" ::: "memory")
#define WAITVM0() asm volatile("s_waitcnt vmcnt(0)" ::: "memory")
#define WAITLGKM0() do { asm volatile("s_waitcnt lgkmcnt(0)" ::: "memory"); \
                         __builtin_amdgcn_sched_barrier(0); } while (0)
#define SBAR() __builtin_amdgcn_s_barrier()

__device__ __forceinline__ unsigned short f2bf(float f) {
  unsigned int u = __float_as_uint(f);
  u += 0x7fffu + ((u >> 16) & 1u);   // RNE
  return (unsigned short)(u >> 16);
}
__device__ __forceinline__ float bf2f(unsigned short u) {
  return __uint_as_float(((unsigned int)u) << 16);
}

// f32 -> fp8 e4m3fn (OCP), input must be >= 0 and <= 448
__device__ __forceinline__ unsigned char f2fp8(float f) {
  unsigned u = __float_as_uint(f);
  unsigned lsb = (u >> 20) & 1u;
  u += 0x7FFFFu + lsb;                 // RNE at mantissa bit 20
  int e = (int)((u >> 23) & 255u) - 120;
  if (e <= 0) {                        // subnormal: units of 2^-9
    int q = (int)(f * 512.f + 0.5f);   // q in [0,8]; 8 rolls into first normal
    return (unsigned char)q;
  }
  if (e > 15) return 0x7E;             // clamp to 448
  return (unsigned char)((e << 3) | ((u >> 20) & 7u));
}
__device__ __forceinline__ unsigned char f2fp8s(float f) {  // signed
  unsigned s = __float_as_uint(f) >> 31;
  float a = fminf(fabsf(f), 448.f);
  return (unsigned char)((s << 7) | f2fp8(a));
}

// ---------------- f32 -> bf16 bulk convert (input) ----------------
__global__ __launch_bounds__(256) void cvt_kernel(const float4* __restrict__ src,
                                                  ushort4* __restrict__ dst, int n4) {
  int i = blockIdx.x * 256 + threadIdx.x;
  int st = gridDim.x * 256;
  for (; i < n4; i += st) {
    float4 v = src[i];
    ushort4 o;
    o.x = f2bf(v.x); o.y = f2bf(v.y); o.z = f2bf(v.z); o.w = f2bf(v.w);
    dst[i] = o;
  }
}

// ---- all-weights convert: wq/w1 -> bf16; wo -> fp8 (x64); w2 -> fp8 (x64) ----
__global__ __launch_bounds__(256) void cvtw_kernel(const float4* __restrict__ wq, ushort4* __restrict__ dq,
                                                   const float4* __restrict__ wo, uchar4* __restrict__ dov,
                                                   const float4* __restrict__ w1, ushort4* __restrict__ d1,
                                                   const float4* __restrict__ w2, uchar4* __restrict__ d2) {
  const int n0 = 98304, n1 = 32768, n2 = 131072, n3 = 131072;  // float4 counts
  int i = blockIdx.x * 256 + threadIdx.x;
  int st = gridDim.x * 256;
  for (; i < n0 + n1 + n2 + n3; i += st) {
    int j = i;
    if (j < n0) {
      float4 v = wq[j];
      dq[j] = (ushort4){f2bf(v.x), f2bf(v.y), f2bf(v.z), f2bf(v.w)};
    } else if ((j -= n0) < n1) {
      float4 v = wo[j];
      dov[j] = (uchar4){f2fp8s(v.x * 64.f), f2fp8s(v.y * 64.f),
                        f2fp8s(v.z * 64.f), f2fp8s(v.w * 64.f)};
    } else if ((j -= n1) < n2) {
      float4 v = w1[j];
      d1[j] = (ushort4){f2bf(v.x), f2bf(v.y), f2bf(v.z), f2bf(v.w)};
    } else {
      j -= n2;
      float4 v = w2[j];
      d2[j] = (uchar4){f2fp8s(v.x * 64.f), f2fp8s(v.y * 64.f),
                       f2fp8s(v.z * 64.f), f2fp8s(v.w * 64.f)};
    }
  }
}

// ---- merged setup: block 0 = tanh(mu) table; block 1 = pi/A softmax ----
__global__ void mtpi_kernel(const float* __restrict__ mus, unsigned short* __restrict__ mtb,
                            float* __restrict__ mtn,
                            const float* __restrict__ il, const float* __restrict__ tl,
                            float* __restrict__ d_pi, float* __restrict__ d_A,
                            float* __restrict__ d_ent) {
  int lane = threadIdx.x;
  if (blockIdx.x == 0) {
    if (lane < 32) {
      float acc = 0.f;
      for (int d = 0; d < 256; d++) {
        float t = tanhf(mus[lane * 256 + d]);
        mtb[lane * 264 + d] = f2bf(t);
        acc += t * t;
      }
      mtn[lane] = acc;
    }
  } else {
    if (lane == 0) *d_ent = 0.f;
    if (lane < 32) {
      float v = il[lane];
      float mx = v;
      #pragma unroll
      for (int off = 16; off; off >>= 1) mx = fmaxf(mx, __shfl_xor(mx, off, 32));
      float e = expf(v - mx), sm = e;
      #pragma unroll
      for (int off = 16; off; off >>= 1) sm += __shfl_xor(sm, off, 32);
      d_pi[lane] = e / sm;
      for (int r = 0; r < 32; r++) {
        float a = tl[r * 32 + lane];
        float m2 = a;
        #pragma unroll
        for (int off = 16; off; off >>= 1) m2 = fmaxf(m2, __shfl_xor(m2, off, 32));
        float e2 = expf(a - m2), s2 = e2;
        #pragma unroll
        for (int off = 16; off; off >>= 1) s2 += __shfl_xor(s2, off, 32);
        d_A[r * 32 + lane] = e2 / s2;
      }
    }
  }
}

// ======== 128x128 tile, BK=32, 4-wave, counted-vmcnt pipelined NT GEMM ========
// (R7-proven structure) EPI 0: bf16 out; 1: relu -> fp8 e4m3 (x8 scale).
template <int EPI>
__global__ __launch_bounds__(256, 4) void gemm_nt(const unsigned short* __restrict__ A,
                                                  const unsigned short* __restrict__ Bw,
                                                  const float* __restrict__ bias,
                                                  void* __restrict__ outp,
                                                  int N, int K, int nx) {
  __shared__ unsigned short lds[16384];   // 32 KB: [2 buf][A 4096 | B 4096]
  const int t = threadIdx.x;
  const int bid = blockIdx.x, nwg = gridDim.x;
  const int wg = (bid & 7) * (nwg >> 3) + (bid >> 3);   // nwg % 8 == 0
  const int m0 = (wg / nx) << 7;
  const int n0 = (wg % nx) << 7;
  const int lane = t & 63, w = t >> 6;
  const int wm = w >> 1, wn = w & 1;      // 2x2 waves, wave tile 64x64
  const int lr = lane & 15, lk = lane >> 4;

  const int r0 = t >> 2, sg = t & 3;
  const int s0 = sg ^ ((r0 >> 1) & 3);
  const int r1 = r0 + 64;
  const int s1 = sg ^ ((r1 >> 1) & 3);
  const int aoff0 = (m0 + r0) * K + s0 * 8;
  const int aoff1 = (m0 + r1) * K + s1 * 8;
  const int boff0 = (n0 + r0) * K + s0 * 8;
  const int boff1 = (n0 + r1) * K + s1 * 8;

#define STAGE(buf, k0) do {                                    \
    char* la = (char*)lds + (buf) * 16384;                     \
    GLOAD_LDS16(A + aoff0 + (k0), la + t * 16);                \
    GLOAD_LDS16(A + aoff1 + (k0), la + 4096 + t * 16);         \
    GLOAD_LDS16(Bw + boff0 + (k0), la + 8192 + t * 16);        \
    GLOAD_LDS16(Bw + boff1 + (k0), la + 12288 + t * 16);       \
  } while (0)

  f32x4 acc[4][4];
  #pragma unroll
  for (int i = 0; i < 4; i++)
    #pragma unroll
    for (int j = 0; j < 4; j++) acc[i][j] = (f32x4)(0.f);

  const int ra = wm * 64 + lr, rb = wn * 64 + lr;
  const int sla = lk ^ ((ra >> 1) & 3), slb = lk ^ ((rb >> 1) & 3);

  const int NT = K >> 5;
  STAGE(0, 0);
  STAGE(1, 32);
  WAITVM4();
  SBAR();

  int c = 0;
  for (int kt = 0; kt < NT; kt++) {
    s16x8 af[4], bf[4];
    {
      const unsigned short* ua = lds + c * 8192;
      const unsigned short* ub = ua + 4096;
      #pragma unroll
      for (int mf = 0; mf < 4; mf++)
        af[mf] = *(const s16x8*)&ua[(ra + mf * 16) * 32 + sla * 8];
      #pragma unroll
      for (int nf = 0; nf < 4; nf++)
        bf[nf] = *(const s16x8*)&ub[(rb + nf * 16) * 32 + slb * 8];
    }
    __builtin_amdgcn_s_setprio(1);
    #pragma unroll
    for (int mf = 0; mf < 4; mf++)
      #pragma unroll
      for (int nf = 0; nf < 4; nf++)
        acc[mf][nf] = __builtin_amdgcn_mfma_f32_16x16x32_bf16(af[mf], bf[nf], acc[mf][nf], 0, 0, 0);
    __builtin_amdgcn_s_setprio(0);
    SBAR();
    if (kt < NT - 2) {
      STAGE(c, (kt + 2) << 5);
      WAITVM4();
    } else if (kt == NT - 2) {
      WAITVM0();
    }
    SBAR();
    c ^= 1;
  }
#undef STAGE

  #pragma unroll
  for (int nf = 0; nf < 4; nf++) {
    int col = n0 + wn * 64 + nf * 16 + lr;
    float bv = bias[col];
    #pragma unroll
    for (int mf = 0; mf < 4; mf++)
      #pragma unroll
      for (int r = 0; r < 4; r++) {
        int row = m0 + wm * 64 + mf * 16 + lk * 4 + r;
        size_t o = (size_t)row * N + col;
        float v = acc[mf][nf][r] + bv;
        if (EPI == 0) {
          ((unsigned short*)outp)[o] = f2bf(v);
        } else {
          float h = fminf(fmaxf(v, 0.f) * 8.f, 448.f);
          ((unsigned char*)outp)[o] = f2fp8(h);
        }
      }
  }
}

// ---- fp8 GEMM (BM=128, BN=256 full width) + bias + residual + LayerNorm ----
// A, B fp8 (pre-scaled); acc rescaled by isc. LDS: A [2 units][128 rows][32 B]
// then B [2 units][256 rows][32 B]. Staging dst LINEAR (wave-uniform-base
// rule); global SOURCE per-lane permuted to match. (R15-validated)
template <bool WR32>
__global__ __launch_bounds__(512) void gemm_ln_fp8(const unsigned char* __restrict__ A,
                                                   const unsigned char* __restrict__ Bw,
                                                   const float* __restrict__ bias,
                                                   const unsigned short* __restrict__ res,
                                                   const float* __restrict__ g,
                                                   const float* __restrict__ bta,
                                                   unsigned short* __restrict__ xb,
                                                   float* __restrict__ x32,
                                                   int K, float isc) {
  __shared__ unsigned char lds8[24576];   // A 8192 B | B 16384 B
  float* stats = (float*)lds8;            // 4 KB, post-loop only
  const int t = threadIdx.x;
  const int nwg = gridDim.x;
  const int bid = blockIdx.x;
  const int wg = (bid & 7) * (nwg >> 3) + (bid >> 3);
  const int m0 = wg << 7;

  const int lane = t & 63, w = t >> 6;
  const int wm = w >> 2, wn = w & 3;
  const int lr = lane & 15, lk = lane >> 4;

  // A: idx t in [0,512) -> unit t>>8, row (t>>1)&127, seg t&1
  const int auu = t >> 8, arow = (t >> 1) & 127, asg = t & 1;
  const size_t aoff = (size_t)(m0 + arow) * K + auu * 32 + asg * 16;
  // B: idx p*512+t in [0,1024) -> unit idx>>9, row (idx>>1)&255, seg idx&1
  size_t boff[2];
  #pragma unroll
  for (int p = 0; p < 2; p++) {
    int idx = p * 512 + t;
    int buu = idx >> 9, brow = (idx >> 1) & 255, bsg = idx & 1;
    boff[p] = (size_t)brow * K + buu * 32 + bsg * 16;
  }

  f32x4 acc[4][4];
  #pragma unroll
  for (int i = 0; i < 4; i++)
    #pragma unroll
    for (int j = 0; j < 4; j++) acc[i][j] = (f32x4)(0.f);

  for (int k0 = 0; k0 < K; k0 += 64) {
    GLOAD_LDS16(A + aoff + k0, (char*)lds8 + t * 16);
    GLOAD_LDS16(Bw + boff[0] + k0, (char*)lds8 + 8192 + t * 16);
    GLOAD_LDS16(Bw + boff[1] + k0, (char*)lds8 + 16384 + t * 16);
    __syncthreads();
    #pragma unroll
    for (int kk = 0; kk < 2; kk++) {
      long long af[4], bf[4];
      #pragma unroll
      for (int mf = 0; mf < 4; mf++)
        af[mf] = *(const long long*)&lds8[kk * 4096 + (wm * 64 + mf * 16 + lr) * 32 + lk * 8];
      #pragma unroll
      for (int nf = 0; nf < 4; nf++)
        bf[nf] = *(const long long*)&lds8[8192 + kk * 8192 + (wn * 64 + nf * 16 + lr) * 32 + lk * 8];
      #pragma unroll
      for (int mf = 0; mf < 4; mf++)
        #pragma unroll
        for (int nf = 0; nf < 4; nf++)
          acc[mf][nf] = __builtin_amdgcn_mfma_f32_16x16x32_fp8_fp8(af[mf], bf[nf], acc[mf][nf], 0, 0, 0);
    }
    __syncthreads();
  }

  float bv[4];
  #pragma unroll
  for (int nf = 0; nf < 4; nf++) bv[nf] = bias[wn * 64 + nf * 16 + lr];

  #pragma unroll
  for (int mf = 0; mf < 4; mf++) {
    #pragma unroll
    for (int r = 0; r < 4; r++) {
      int grow = m0 + wm * 64 + mf * 16 + lk * 4 + r;
      float s = 0.f, q = 0.f;
      #pragma unroll
      for (int nf = 0; nf < 4; nf++) {
        int col = wn * 64 + nf * 16 + lr;
        float v = acc[mf][nf][r] * isc + bv[nf] + bf2f(res[(size_t)grow * 256 + col]);
        acc[mf][nf][r] = v;
        s += v; q += v * v;
      }
      #pragma unroll
      for (int off = 1; off < 16; off <<= 1) { s += __shfl_xor(s, off); q += __shfl_xor(q, off); }
      if (lr == 0) {
        int lrow = wm * 64 + mf * 16 + lk * 4 + r;
        stats[lrow * 4 + wn] = s;
        stats[512 + lrow * 4 + wn] = q;
      }
    }
  }
  __syncthreads();

  float gv[4], bbv[4];
  #pragma unroll
  for (int nf = 0; nf < 4; nf++) {
    int col = wn * 64 + nf * 16 + lr;
    gv[nf] = g[col]; bbv[nf] = bta[col];
  }
  #pragma unroll
  for (int mf = 0; mf < 4; mf++) {
    #pragma unroll
    for (int r = 0; r < 4; r++) {
      int lrow = wm * 64 + mf * 16 + lk * 4 + r;
      int grow = m0 + lrow;
      float s4 = stats[lrow * 4 + 0] + stats[lrow * 4 + 1] + stats[lrow * 4 + 2] + stats[lrow * 4 + 3];
      float q4 = stats[512 + lrow * 4 + 0] + stats[512 + lrow * 4 + 1]
               + stats[512 + lrow * 4 + 2] + stats[512 + lrow * 4 + 3];
      float mean = s4 * (1.f / 256.f);
      float var = q4 * (1.f / 256.f) - mean * mean;
      float rs = rsqrtf(var + 1e-5f);
      #pragma unroll
      for (int nf = 0; nf < 4; nf++) {
        int col = wn * 64 + nf * 16 + lr;
        float val = (acc[mf][nf][r] - mean) * rs * gv[nf] + bbv[nf];
        xb[(size_t)grow * 256 + col] = f2bf(val);
        if (WR32) x32[(size_t)grow * 256 + col] = val;
      }
    }
  }
}

// ---------------- attention: one wave per (b,h), compact LDS, V^T ----------
// (R11-proven; epilogue now writes fp8 x16 for the fp8 Wo projection)
__global__ __launch_bounds__(64) void attn_kernel(const unsigned short* __restrict__ qkv,
                                                  unsigned char* __restrict__ ob) {
  __shared__ unsigned short al[6784];   // 13568 B
  unsigned short* qs = al;
  unsigned short* ks = al + 2048;
  unsigned short* vs = al + 4608;
  unsigned short* vt = al;              // [32][68]
  unsigned short* ps = al + 2176;       // [64][72]
  const int bh = blockIdx.x;
  const int b = bh >> 3, h = bh & 7;
  const int lane = threadIdx.x;
  const int lr = lane & 15, lk = lane >> 4;

  #pragma unroll
  for (int p = 0; p < 4; p++) {
    int u = lane + p * 64;
    int row = u >> 2, seg = u & 3;
    size_t gb = (size_t)(b * 64 + row) * 768 + h * 32 + seg * 8;
    GLOAD_LDS16(qkv + gb, (char*)al + u * 16);
    GLOAD_LDS16(qkv + gb + 256, (char*)al + 4096 + u * 16);
    GLOAD_LDS16(qkv + gb + 512, (char*)al + 9216 + u * 16);
  }
  __syncthreads();

  s16x8 aq[4], bk[4], vchunk[4];
  #pragma unroll
  for (int mi = 0; mi < 4; mi++) aq[mi] = *(const s16x8*)&qs[(mi * 16 + lr) * 32 + lk * 8];
  #pragma unroll
  for (int nj = 0; nj < 4; nj++) bk[nj] = *(const s16x8*)&ks[(nj * 16 + lr) * 32 + lk * 8];
  const int vrow = lane >> 2, vcs = (lane & 3) * 8;
  #pragma unroll
  for (int q = 0; q < 4; q++)
    vchunk[q] = *(const s16x8*)&vs[(q * 16 + vrow) * 32 + vcs];
  WAITLGKM0();

  #pragma unroll
  for (int q = 0; q < 4; q++)
    #pragma unroll
    for (int j = 0; j < 8; j++)
      vt[(vcs + j) * 68 + q * 16 + vrow] = (unsigned short)vchunk[q][j];

  f32x4 s[4][4];
  #pragma unroll
  for (int i = 0; i < 4; i++)
    #pragma unroll
    for (int j = 0; j < 4; j++) s[i][j] = (f32x4)(0.f);
  #pragma unroll
  for (int mi = 0; mi < 4; mi++)
    #pragma unroll
    for (int nj = 0; nj < 4; nj++)
      s[mi][nj] = __builtin_amdgcn_mfma_f32_16x16x32_bf16(aq[mi], bk[nj], s[mi][nj], 0, 0, 0);

  const float scale = 0.17677669529663687f;
  #pragma unroll
  for (int mi = 0; mi < 4; mi++) {
    #pragma unroll
    for (int r = 0; r < 4; r++) {
      float t0 = s[mi][0][r] * scale, t1 = s[mi][1][r] * scale;
      float t2 = s[mi][2][r] * scale, t3 = s[mi][3][r] * scale;
      float mx = fmaxf(fmaxf(t0, t1), fmaxf(t2, t3));
      #pragma unroll
      for (int off = 8; off; off >>= 1) mx = fmaxf(mx, __shfl_xor(mx, off, 16));
      float e0 = expf(t0 - mx), e1 = expf(t1 - mx), e2 = expf(t2 - mx), e3 = expf(t3 - mx);
      float sm = e0 + e1 + e2 + e3;
      #pragma unroll
      for (int off = 8; off; off >>= 1) sm += __shfl_xor(sm, off, 16);
      float inv = 1.f / sm;
      int prow = mi * 16 + lk * 4 + r;
      ps[prow * 72 + lr + 0]  = f2bf(e0 * inv);
      ps[prow * 72 + lr + 16] = f2bf(e1 * inv);
      ps[prow * 72 + lr + 32] = f2bf(e2 * inv);
      ps[prow * 72 + lr + 48] = f2bf(e3 * inv);
    }
  }
  WAITLGKM0();

  f32x4 oacc[4][2];
  #pragma unroll
  for (int i = 0; i < 4; i++) { oacc[i][0] = (f32x4)(0.f); oacc[i][1] = (f32x4)(0.f); }
  #pragma unroll
  for (int kk = 0; kk < 2; kk++) {
    s16x8 bv[2];
    #pragma unroll
    for (int nf = 0; nf < 2; nf++)
      bv[nf] = *(const s16x8*)&vt[(nf * 16 + lr) * 68 + kk * 32 + lk * 8];
    #pragma unroll
    for (int mi = 0; mi < 4; mi++) {
      s16x8 ap = *(const s16x8*)&ps[(mi * 16 + lr) * 72 + kk * 32 + lk * 8];
      #pragma unroll
      for (int nf = 0; nf < 2; nf++)
        oacc[mi][nf] = __builtin_amdgcn_mfma_f32_16x16x32_bf16(ap, bv[nf], oacc[mi][nf], 0, 0, 0);
    }
  }
  #pragma unroll
  for (int mi = 0; mi < 4; mi++)
    #pragma unroll
    for (int nf = 0; nf < 2; nf++)
      #pragma unroll
      for (int r = 0; r < 4; r++) {
        int tok = mi * 16 + lk * 4 + r;
        int c = nf * 16 + lr;
        ob[(size_t)(b * 64 + tok) * 256 + h * 32 + c] = f2fp8s(oacc[mi][nf][r] * 16.f);
      }
}

// -------- cluster probs -> log_emit via MFMA (R12-proven, unchanged) --------
__global__ __launch_bounds__(256) void cluster_kernel(const unsigned short* __restrict__ xb,
                                                      const unsigned short* __restrict__ mtb,
                                                      const float* __restrict__ mtn,
                                                      float* __restrict__ log_emit) {
  __shared__ unsigned short ms[32 * 264];   // 16.5 KB
  const int t = threadIdx.x;
  for (int i = t; i < 2112; i += 256)
    ((uint2*)ms)[i] = ((const uint2*)mtb)[i];
  const int lane = t & 63, w = t >> 6;
  const int lr = lane & 15, lk = lane >> 4;
  const float mtn0 = mtn[lr], mtn1 = mtn[16 + lr];
  __syncthreads();

  const size_t tok0 = (size_t)blockIdx.x * 256 + (size_t)w * 64;
  f32x4 s[4][2];
  #pragma unroll
  for (int i = 0; i < 4; i++) { s[i][0] = (f32x4)(0.f); s[i][1] = (f32x4)(0.f); }

  #pragma unroll
  for (int kk = 0; kk < 8; kk++) {
    s16x8 bf0 = *(const s16x8*)&ms[lr * 264 + lk * 8 + kk * 32];
    s16x8 bf1 = *(const s16x8*)&ms[(16 + lr) * 264 + lk * 8 + kk * 32];
    #pragma unroll
    for (int mi = 0; mi < 4; mi++) {
      s16x8 af = *(const s16x8*)&xb[(tok0 + mi * 16 + lr) * 256 + lk * 8 + kk * 32];
      s[mi][0] = __builtin_amdgcn_mfma_f32_16x16x32_bf16(af, bf0, s[mi][0], 0, 0, 0);
      s[mi][1] = __builtin_amdgcn_mfma_f32_16x16x32_bf16(af, bf1, s[mi][1], 0, 0, 0);
    }
  }

  #pragma unroll
  for (int mi = 0; mi < 4; mi++) {
    #pragma unroll
    for (int r = 0; r < 4; r++) {
      float l0 = (2.f * s[mi][0][r] - mtn0) * 0.1f;
      float l1 = (2.f * s[mi][1][r] - mtn1) * 0.1f;
      float mx = fmaxf(l0, l1);
      #pragma unroll
      for (int off = 8; off; off >>= 1) mx = fmaxf(mx, __shfl_xor(mx, off, 16));
      float e0 = expf(l0 - mx), e1 = expf(l1 - mx);
      float sm = e0 + e1;
      #pragma unroll
      for (int off = 8; off; off >>= 1) sm += __shfl_xor(sm, off, 16);
      float inv = 1.f / sm;
      size_t row = tok0 + mi * 16 + lk * 4 + r;
      log_emit[row * 32 + lr]      = logf(e0 * inv + 1e-10f);
      log_emit[row * 32 + 16 + lr] = logf(e1 * inv + 1e-10f);
    }
  }
}

// ---------------- HMM forward scan + entropy ----------------
__global__ __launch_bounds__(256) void scan_kernel(const float* __restrict__ log_emit,
                                                   const float* __restrict__ pi,
                                                   const float* __restrict__ A,
                                                   float* __restrict__ cp,
                                                   float* __restrict__ ent) {
  const int g = threadIdx.x >> 5, j = threadIdx.x & 31;
  const int batch = blockIdx.x * 8 + g;
  float regA[32];
  #pragma unroll
  for (int i = 0; i < 32; i++) regA[i] = A[i * 32 + j];
  const float* le = log_emit + (size_t)batch * 64 * 32;
  float* cpo = cp + (size_t)batch * 64 * 32;

  float u = logf(pi[j] + 1e-10f) + le[j];
  float mx = u;
  #pragma unroll
  for (int off = 16; off; off >>= 1) mx = fmaxf(mx, __shfl_xor(mx, off, 32));
  float e = expf(u - mx), sm = e;
  #pragma unroll
  for (int off = 16; off; off >>= 1) sm += __shfl_xor(sm, off, 32);
  float p = e / sm;
  cpo[j] = p;
  float enta = p * logf(p + 1e-10f);

  for (int n = 1; n < 64; n++) {
    float tt = 0.f;
    #pragma unroll
    for (int i = 0; i < 32; i++) tt += __shfl(p, i, 32) * regA[i];
    u = logf(tt + 1e-10f) + le[n * 32 + j];
    mx = u;
    #pragma unroll
    for (int off = 16; off; off >>= 1) mx = fmaxf(mx, __shfl_xor(mx, off, 32));
    e = expf(u - mx); sm = e;
    #pragma unroll
    for (int off = 16; off; off >>= 1) sm += __shfl_xor(sm, off, 32);
    p = e / sm;
    cpo[n * 32 + j] = p;
    enta += p * logf(p + 1e-10f);
  }
  #pragma unroll
  for (int off = 16; off; off >>= 1) enta += __shfl_xor(enta, off, 32);
  if (j == 0) atomicAdd(ent, -enta * (1.f / (2048.f * 64.f)));
}

// ---------------- launcher ----------------
extern "C" void kernel_launch(void* const* d_in, const int* in_sizes, int n_in,
                              void* d_out, int out_size, void* d_ws, size_t ws_size,
                              hipStream_t stream) {
  const float* input = (const float*)d_in[0];
  const float* init_logits = (const float*)d_in[1];
  const float* trans = (const float*)d_in[2];
  const float* Wqkv = (const float*)d_in[3];
  const float* bqkv = (const float*)d_in[4];
  const float* Wo = (const float*)d_in[5];
  const float* bo = (const float*)d_in[6];
  const float* ln1g = (const float*)d_in[7];
  const float* ln1b = (const float*)d_in[8];
  const float* ln2g = (const float*)d_in[9];
  const float* ln2b = (const float*)d_in[10];
  const float* W1 = (const float*)d_in[11];
  const float* b1 = (const float*)d_in[12];
  const float* W2 = (const float*)d_in[13];
  const float* b2 = (const float*)d_in[14];
  const float* mus = (const float*)d_in[15];

  float* out = (float*)d_out;
  float* cp = out;                  // [BN,32]
  float* x = out + 4194304;         // emb_all [BN,256] f32
  float* d_pi = out + 37748736;
  float* d_A = out + 37748768;
  float* d_ent = out + 37749792;

  char* ws = (char*)d_ws;
  unsigned short* qkv = (unsigned short*)ws;        // region A: qkv -> hb(fp8) -> log_emit
  unsigned char* hb = (unsigned char*)ws;           // [BN][1024] fp8, 128 MB
  float* log_emit = (float*)ws;
  unsigned char* ob = (unsigned char*)(ws + 268435456ull);     // region B: attn out fp8 (x16)
  unsigned short* xb = (unsigned short*)(ws + 335544320ull);   // residual stream bf16
  unsigned short* wq_b = (unsigned short*)(ws + 402653184ull);
  unsigned char* wo_f = (unsigned char*)(ws + 402653184ull + 786432ull);    // fp8 x64
  unsigned short* w1_b = (unsigned short*)(ws + 402653184ull + 1048576ull);
  unsigned char* w2_f = (unsigned char*)(ws + 402653184ull + 2097152ull);   // fp8 x64
  unsigned short* mtb = (unsigned short*)(ws + 402653184ull + 3145728ull);
  float* mtn = (float*)(ws + 402653184ull + 3178496ull);

  cvt_kernel<<<2048, 256, 0, stream>>>((const float4*)input, (ushort4*)xb, BNT * 256 / 4);
  cvtw_kernel<<<512, 256, 0, stream>>>((const float4*)Wqkv, (ushort4*)wq_b,
                                       (const float4*)Wo, (uchar4*)wo_f,
                                       (const float4*)W1, (ushort4*)w1_b,
                                       (const float4*)W2, (uchar4*)w2_f);
  mtpi_kernel<<<2, 64, 0, stream>>>(mus, mtb, mtn, init_logits, trans, d_pi, d_A, d_ent);

  for (int l = 0; l < 2; l++) {
    gemm_nt<0><<<6144, 256, 0, stream>>>(xb, wq_b + l * 196608, bqkv + l * 768,
                                         qkv, 768, 256, 6);
    attn_kernel<<<16384, 64, 0, stream>>>(qkv, ob);
    // Wo projection: A = ob fp8 (x16), B = Wo fp8 (x64) -> isc = 1/1024
    gemm_ln_fp8<false><<<1024, 512, 0, stream>>>(ob, wo_f + l * 65536, bo + l * 256,
                                                 xb, ln1g + l * 256, ln1b + l * 256,
                                                 xb, nullptr, 256, 1.f / 1024.f);
    gemm_nt<1><<<8192, 256, 0, stream>>>(xb, w1_b + l * 262144, b1 + l * 1024,
                                         hb, 1024, 256, 8);
    // FFN2: A = h fp8 (x8), B = W2 fp8 (x64) -> isc = 1/512
    if (l == LLN - 1)
      gemm_ln_fp8<true><<<1024, 512, 0, stream>>>(hb, w2_f + l * 262144, b2 + l * 256,
                                                  xb, ln2g + l * 256, ln2b + l * 256,
                                                  xb, x, 1024, 1.f / 512.f);
    else
      gemm_ln_fp8<false><<<1024, 512, 0, stream>>>(hb, w2_f + l * 262144, b2 + l * 256,
                                                   xb, ln2g + l * 256, ln2b + l * 256,
                                                   xb, nullptr, 1024, 1.f / 512.f);
  }

  cluster_kernel<<<512, 256, 0, stream>>>(xb, mtb, mtn, log_emit);
  scan_kernel<<<256, 256, 0, stream>>>(log_emit, d_pi, d_A, cp, d_ent);
}

// Round 17
// 1075.350 us; speedup vs baseline: 1.0481x; 1.0481x over previous
//
#include <hip/hip_runtime.h>

#define BB   2048
#define NNX  64
#define DD   256
#define KKC  32
#define LLN  2
#define HHN  8
#define DHH  32
#define DFFN 1024
#define BNT  (BB*NNX)   // 131072

typedef short s16x8 __attribute__((ext_vector_type(8)));
typedef float f32x4 __attribute__((ext_vector_type(4)));

#define GLOAD_LDS16(gp, lp) __builtin_amdgcn_global_load_lds( \
    (const __attribute__((address_space(1))) void*)(gp),      \
    (__attribute__((address_space(3))) void*)(lp), 16, 0, 0)

#define WAITVM4() asm volatile("s_waitcnt vmcnt(4)" ::: "memory")
#define WAITVM0() asm volatile("s_waitcnt vmcnt(0)" ::: "memory")
#define WAITLGKM0() do { asm volatile("s_waitcnt lgkmcnt(0)" ::: "memory"); \
                         __builtin_amdgcn_sched_barrier(0); } while (0)
#define SBAR() __builtin_amdgcn_s_barrier()

__device__ __forceinline__ unsigned short f2bf(float f) {
  unsigned int u = __float_as_uint(f);
  u += 0x7fffu + ((u >> 16) & 1u);   // RNE
  return (unsigned short)(u >> 16);
}
__device__ __forceinline__ float bf2f(unsigned short u) {
  return __uint_as_float(((unsigned int)u) << 16);
}

// f32 -> fp8 e4m3fn (OCP), input must be >= 0 and <= 448
__device__ __forceinline__ unsigned char f2fp8(float f) {
  unsigned u = __float_as_uint(f);
  unsigned lsb = (u >> 20) & 1u;
  u += 0x7FFFFu + lsb;                 // RNE at mantissa bit 20
  int e = (int)((u >> 23) & 255u) - 120;
  if (e <= 0) {                        // subnormal: units of 2^-9
    int q = (int)(f * 512.f + 0.5f);   // q in [0,8]; 8 rolls into first normal
    return (unsigned char)q;
  }
  if (e > 15) return 0x7E;             // clamp to 448
  return (unsigned char)((e << 3) | ((u >> 20) & 7u));
}
__device__ __forceinline__ unsigned char f2fp8s(float f) {  // signed
  unsigned s = __float_as_uint(f) >> 31;
  float a = fminf(fabsf(f), 448.f);
  return (unsigned char)((s << 7) | f2fp8(a));
}
// cheap unsigned fp8 (flush tiny to 0) for softmax probabilities
__device__ __forceinline__ unsigned char p2fp8(float f) {
  unsigned u = __float_as_uint(f);
  u += 0x7FFFFu + ((u >> 20) & 1u);
  int e = (int)((u >> 23) & 255u) - 120;
  if (e <= 0) return 0;
  return (unsigned char)((e << 3) | ((u >> 20) & 7u));
}

// ---------------- f32 -> bf16 bulk convert (input) ----------------
__global__ __launch_bounds__(256) void cvt_kernel(const float4* __restrict__ src,
                                                  ushort4* __restrict__ dst, int n4) {
  int i = blockIdx.x * 256 + threadIdx.x;
  int st = gridDim.x * 256;
  for (; i < n4; i += st) {
    float4 v = src[i];
    ushort4 o;
    o.x = f2bf(v.x); o.y = f2bf(v.y); o.z = f2bf(v.z); o.w = f2bf(v.w);
    dst[i] = o;
  }
}

// ---- all-weights convert: wq/wo/w1 -> bf16; w2 -> fp8 e4m3 (x64) ----
__global__ __launch_bounds__(256) void cvtw_kernel(const float4* __restrict__ wq, ushort4* __restrict__ dq,
                                                   const float4* __restrict__ wo, ushort4* __restrict__ dov,
                                                   const float4* __restrict__ w1, ushort4* __restrict__ d1,
                                                   const float4* __restrict__ w2, uchar4* __restrict__ d2) {
  const int n0 = 98304, n1 = 32768, n2 = 131072, n3 = 131072;  // float4 counts
  int i = blockIdx.x * 256 + threadIdx.x;
  int st = gridDim.x * 256;
  for (; i < n0 + n1 + n2 + n3; i += st) {
    int j = i;
    if (j < n0) {
      float4 v = wq[j];
      dq[j] = (ushort4){f2bf(v.x), f2bf(v.y), f2bf(v.z), f2bf(v.w)};
    } else if ((j -= n0) < n1) {
      float4 v = wo[j];
      dov[j] = (ushort4){f2bf(v.x), f2bf(v.y), f2bf(v.z), f2bf(v.w)};
    } else if ((j -= n1) < n2) {
      float4 v = w1[j];
      d1[j] = (ushort4){f2bf(v.x), f2bf(v.y), f2bf(v.z), f2bf(v.w)};
    } else {
      j -= n2;
      float4 v = w2[j];
      d2[j] = (uchar4){f2fp8s(v.x * 64.f), f2fp8s(v.y * 64.f),
                       f2fp8s(v.z * 64.f), f2fp8s(v.w * 64.f)};
    }
  }
}

// ---- merged setup: block 0 = tanh(mu) table; block 1 = pi/A softmax ----
__global__ void mtpi_kernel(const float* __restrict__ mus, unsigned short* __restrict__ mtb,
                            float* __restrict__ mtn,
                            const float* __restrict__ il, const float* __restrict__ tl,
                            float* __restrict__ d_pi, float* __restrict__ d_A,
                            float* __restrict__ d_ent) {
  int lane = threadIdx.x;
  if (blockIdx.x == 0) {
    if (lane < 32) {
      float acc = 0.f;
      for (int d = 0; d < 256; d++) {
        float t = tanhf(mus[lane * 256 + d]);
        mtb[lane * 264 + d] = f2bf(t);
        acc += t * t;
      }
      mtn[lane] = acc;
    }
  } else {
    if (lane == 0) *d_ent = 0.f;
    if (lane < 32) {
      float v = il[lane];
      float mx = v;
      #pragma unroll
      for (int off = 16; off; off >>= 1) mx = fmaxf(mx, __shfl_xor(mx, off, 32));
      float e = expf(v - mx), sm = e;
      #pragma unroll
      for (int off = 16; off; off >>= 1) sm += __shfl_xor(sm, off, 32);
      d_pi[lane] = e / sm;
      for (int r = 0; r < 32; r++) {
        float a = tl[r * 32 + lane];
        float m2 = a;
        #pragma unroll
        for (int off = 16; off; off >>= 1) m2 = fmaxf(m2, __shfl_xor(m2, off, 32));
        float e2 = expf(a - m2), s2 = e2;
        #pragma unroll
        for (int off = 16; off; off >>= 1) s2 += __shfl_xor(s2, off, 32);
        d_A[r * 32 + lane] = e2 / s2;
      }
    }
  }
}

// ======== 128x128 tile, BK=32, 4-wave, counted-vmcnt pipelined NT GEMM ========
// EPI 0: bf16 out; 1: relu -> fp8 (x8); 2: fp8 signed (x32, for qkv).
template <int EPI>
__global__ __launch_bounds__(256, 4) void gemm_nt(const unsigned short* __restrict__ A,
                                                  const unsigned short* __restrict__ Bw,
                                                  const float* __restrict__ bias,
                                                  void* __restrict__ outp,
                                                  int N, int K, int nx) {
  __shared__ unsigned short lds[16384];   // 32 KB: [2 buf][A 4096 | B 4096]
  const int t = threadIdx.x;
  const int bid = blockIdx.x, nwg = gridDim.x;
  const int wg = (bid & 7) * (nwg >> 3) + (bid >> 3);   // nwg % 8 == 0
  const int m0 = (wg / nx) << 7;
  const int n0 = (wg % nx) << 7;
  const int lane = t & 63, w = t >> 6;
  const int wm = w >> 1, wn = w & 1;      // 2x2 waves, wave tile 64x64
  const int lr = lane & 15, lk = lane >> 4;

  const int r0 = t >> 2, sg = t & 3;
  const int s0 = sg ^ ((r0 >> 1) & 3);
  const int r1 = r0 + 64;
  const int s1 = sg ^ ((r1 >> 1) & 3);
  const int aoff0 = (m0 + r0) * K + s0 * 8;
  const int aoff1 = (m0 + r1) * K + s1 * 8;
  const int boff0 = (n0 + r0) * K + s0 * 8;
  const int boff1 = (n0 + r1) * K + s1 * 8;

#define STAGE(buf, k0) do {                                    \
    char* la = (char*)lds + (buf) * 16384;                     \
    GLOAD_LDS16(A + aoff0 + (k0), la + t * 16);                \
    GLOAD_LDS16(A + aoff1 + (k0), la + 4096 + t * 16);         \
    GLOAD_LDS16(Bw + boff0 + (k0), la + 8192 + t * 16);        \
    GLOAD_LDS16(Bw + boff1 + (k0), la + 12288 + t * 16);       \
  } while (0)

  f32x4 acc[4][4];
  #pragma unroll
  for (int i = 0; i < 4; i++)
    #pragma unroll
    for (int j = 0; j < 4; j++) acc[i][j] = (f32x4)(0.f);

  const int ra = wm * 64 + lr, rb = wn * 64 + lr;
  const int sla = lk ^ ((ra >> 1) & 3), slb = lk ^ ((rb >> 1) & 3);

  const int NT = K >> 5;
  STAGE(0, 0);
  STAGE(1, 32);
  WAITVM4();
  SBAR();

  int c = 0;
  for (int kt = 0; kt < NT; kt++) {
    s16x8 af[4], bf[4];
    {
      const unsigned short* ua = lds + c * 8192;
      const unsigned short* ub = ua + 4096;
      #pragma unroll
      for (int mf = 0; mf < 4; mf++)
        af[mf] = *(const s16x8*)&ua[(ra + mf * 16) * 32 + sla * 8];
      #pragma unroll
      for (int nf = 0; nf < 4; nf++)
        bf[nf] = *(const s16x8*)&ub[(rb + nf * 16) * 32 + slb * 8];
    }
    __builtin_amdgcn_s_setprio(1);
    #pragma unroll
    for (int mf = 0; mf < 4; mf++)
      #pragma unroll
      for (int nf = 0; nf < 4; nf++)
        acc[mf][nf] = __builtin_amdgcn_mfma_f32_16x16x32_bf16(af[mf], bf[nf], acc[mf][nf], 0, 0, 0);
    __builtin_amdgcn_s_setprio(0);
    SBAR();
    if (kt < NT - 2) {
      STAGE(c, (kt + 2) << 5);
      WAITVM4();
    } else if (kt == NT - 2) {
      WAITVM0();
    }
    SBAR();
    c ^= 1;
  }
#undef STAGE

  #pragma unroll
  for (int nf = 0; nf < 4; nf++) {
    int col = n0 + wn * 64 + nf * 16 + lr;
    float bv = bias[col];
    #pragma unroll
    for (int mf = 0; mf < 4; mf++)
      #pragma unroll
      for (int r = 0; r < 4; r++) {
        int row = m0 + wm * 64 + mf * 16 + lk * 4 + r;
        size_t o = (size_t)row * N + col;
        float v = acc[mf][nf][r] + bv;
        if (EPI == 0) {
          ((unsigned short*)outp)[o] = f2bf(v);
        } else if (EPI == 1) {
          float hh = fminf(fmaxf(v, 0.f) * 8.f, 448.f);
          ((unsigned char*)outp)[o] = f2fp8(hh);
        } else {
          ((unsigned char*)outp)[o] = f2fp8s(v * 32.f);
        }
      }
  }
}

// ------- GEMM (BM=128, BN=256 full width) + bias + residual + LayerNorm -------
// (R4-measured bf16 version; used for the Wo projection, K=256)
template <bool WR32>
__global__ __launch_bounds__(512) void gemm_ln(const unsigned short* __restrict__ A,
                                               const unsigned short* __restrict__ Bw,
                                               const float* __restrict__ bias,
                                               const unsigned short* __restrict__ res,
                                               const float* __restrict__ g,
                                               const float* __restrict__ bta,
                                               unsigned short* __restrict__ xb,
                                               float* __restrict__ x32,
                                               int K) {
  __shared__ unsigned short As[128 * 64];
  __shared__ unsigned short Bs[256 * 64];
  __shared__ float stats[2][128][4];
  const int t = threadIdx.x;
  const int nwg = gridDim.x;
  const int bid = blockIdx.x;
  const int wg = (bid & 7) * (nwg >> 3) + (bid >> 3);
  const int m0 = wg << 7;

  const int lane = t & 63, w = t >> 6;
  const int wm = w >> 2, wn = w & 3;
  const int lr = lane & 15, lk = lane >> 4;

  size_t aoff[2], boff[4];
  #pragma unroll
  for (int p = 0; p < 2; p++) {
    int u = p * 512 + t;
    int row = u >> 3, sp = u & 7;
    int seg = sp ^ (((row >> 2) & 1) << 1);
    aoff[p] = (size_t)(m0 + row) * K + seg * 8;
  }
  #pragma unroll
  for (int p = 0; p < 4; p++) {
    int u = p * 512 + t;
    int row = u >> 3, sp = u & 7;
    int seg = sp ^ (((row >> 2) & 1) << 1);
    boff[p] = (size_t)row * K + seg * 8;
  }

  f32x4 acc[4][4];
  #pragma unroll
  for (int i = 0; i < 4; i++)
    #pragma unroll
    for (int j = 0; j < 4; j++) acc[i][j] = (f32x4)(0.f);

  for (int k0 = 0; k0 < K; k0 += 64) {
    #pragma unroll
    for (int p = 0; p < 2; p++)
      GLOAD_LDS16(A + aoff[p] + k0, (char*)As + (p * 512 + t) * 16);
    #pragma unroll
    for (int p = 0; p < 4; p++)
      GLOAD_LDS16(Bw + boff[p] + k0, (char*)Bs + (p * 512 + t) * 16);
    __syncthreads();
    #pragma unroll
    for (int z = 0; z < 2; z++) {
      s16x8 af[4], bfr[4];
      #pragma unroll
      for (int mf = 0; mf < 4; mf++) {
        int row = wm * 64 + mf * 16 + lr;
        int cc = (z * 4 + lk) ^ (((row >> 2) & 1) << 1);
        af[mf] = *(const s16x8*)&As[row * 64 + cc * 8];
      }
      #pragma unroll
      for (int nf = 0; nf < 4; nf++) {
        int row = wn * 64 + nf * 16 + lr;
        int cc = (z * 4 + lk) ^ (((row >> 2) & 1) << 1);
        bfr[nf] = *(const s16x8*)&Bs[row * 64 + cc * 8];
      }
      #pragma unroll
      for (int mf = 0; mf < 4; mf++)
        #pragma unroll
        for (int nf = 0; nf < 4; nf++)
          acc[mf][nf] = __builtin_amdgcn_mfma_f32_16x16x32_bf16(af[mf], bfr[nf], acc[mf][nf], 0, 0, 0);
    }
    __syncthreads();
  }

  float bv[4];
  #pragma unroll
  for (int nf = 0; nf < 4; nf++) bv[nf] = bias[wn * 64 + nf * 16 + lr];

  #pragma unroll
  for (int mf = 0; mf < 4; mf++) {
    #pragma unroll
    for (int r = 0; r < 4; r++) {
      int grow = m0 + wm * 64 + mf * 16 + lk * 4 + r;
      float s = 0.f, q = 0.f;
      #pragma unroll
      for (int nf = 0; nf < 4; nf++) {
        int col = wn * 64 + nf * 16 + lr;
        float v = acc[mf][nf][r] + bv[nf] + bf2f(res[(size_t)grow * 256 + col]);
        acc[mf][nf][r] = v;
        s += v; q += v * v;
      }
      #pragma unroll
      for (int off = 1; off < 16; off <<= 1) { s += __shfl_xor(s, off); q += __shfl_xor(q, off); }
      if (lr == 0) {
        int lrow = wm * 64 + mf * 16 + lk * 4 + r;
        stats[0][lrow][wn] = s;
        stats[1][lrow][wn] = q;
      }
    }
  }
  __syncthreads();

  float gv[4], bbv[4];
  #pragma unroll
  for (int nf = 0; nf < 4; nf++) {
    int col = wn * 64 + nf * 16 + lr;
    gv[nf] = g[col]; bbv[nf] = bta[col];
  }
  #pragma unroll
  for (int mf = 0; mf < 4; mf++) {
    #pragma unroll
    for (int r = 0; r < 4; r++) {
      int lrow = wm * 64 + mf * 16 + lk * 4 + r;
      int grow = m0 + lrow;
      float s4 = stats[0][lrow][0] + stats[0][lrow][1] + stats[0][lrow][2] + stats[0][lrow][3];
      float q4 = stats[1][lrow][0] + stats[1][lrow][1] + stats[1][lrow][2] + stats[1][lrow][3];
      float mean = s4 * (1.f / 256.f);
      float var = q4 * (1.f / 256.f) - mean * mean;
      float rs = rsqrtf(var + 1e-5f);
      #pragma unroll
      for (int nf = 0; nf < 4; nf++) {
        int col = wn * 64 + nf * 16 + lr;
        float val = (acc[mf][nf][r] - mean) * rs * gv[nf] + bbv[nf];
        xb[(size_t)grow * 256 + col] = f2bf(val);
        if (WR32) x32[(size_t)grow * 256 + col] = val;
      }
    }
  }
}

// ---- fp8 GEMM (BM=128, BN=256 full width) + bias + residual + LayerNorm ----
// (R15-validated; FFN2 only, isc = 1/512)
template <bool WR32>
__global__ __launch_bounds__(512) void gemm_ln_fp8(const unsigned char* __restrict__ A,
                                                   const unsigned char* __restrict__ Bw,
                                                   const float* __restrict__ bias,
                                                   const unsigned short* __restrict__ res,
                                                   const float* __restrict__ g,
                                                   const float* __restrict__ bta,
                                                   unsigned short* __restrict__ xb,
                                                   float* __restrict__ x32,
                                                   int K) {
  __shared__ unsigned char lds8[24576];   // A 8192 B | B 16384 B
  float* stats = (float*)lds8;            // 4 KB, post-loop only
  const int t = threadIdx.x;
  const int nwg = gridDim.x;
  const int bid = blockIdx.x;
  const int wg = (bid & 7) * (nwg >> 3) + (bid >> 3);
  const int m0 = wg << 7;

  const int lane = t & 63, w = t >> 6;
  const int wm = w >> 2, wn = w & 3;
  const int lr = lane & 15, lk = lane >> 4;

  const int auu = t >> 8, arow = (t >> 1) & 127, asg = t & 1;
  const size_t aoff = (size_t)(m0 + arow) * K + auu * 32 + asg * 16;
  size_t boff[2];
  #pragma unroll
  for (int p = 0; p < 2; p++) {
    int idx = p * 512 + t;
    int buu = idx >> 9, brow = (idx >> 1) & 255, bsg = idx & 1;
    boff[p] = (size_t)brow * K + buu * 32 + bsg * 16;
  }

  f32x4 acc[4][4];
  #pragma unroll
  for (int i = 0; i < 4; i++)
    #pragma unroll
    for (int j = 0; j < 4; j++) acc[i][j] = (f32x4)(0.f);

  for (int k0 = 0; k0 < K; k0 += 64) {
    GLOAD_LDS16(A + aoff + k0, (char*)lds8 + t * 16);
    GLOAD_LDS16(Bw + boff[0] + k0, (char*)lds8 + 8192 + t * 16);
    GLOAD_LDS16(Bw + boff[1] + k0, (char*)lds8 + 16384 + t * 16);
    __syncthreads();
    #pragma unroll
    for (int kk = 0; kk < 2; kk++) {
      long long af[4], bf[4];
      #pragma unroll
      for (int mf = 0; mf < 4; mf++)
        af[mf] = *(const long long*)&lds8[kk * 4096 + (wm * 64 + mf * 16 + lr) * 32 + lk * 8];
      #pragma unroll
      for (int nf = 0; nf < 4; nf++)
        bf[nf] = *(const long long*)&lds8[8192 + kk * 8192 + (wn * 64 + nf * 16 + lr) * 32 + lk * 8];
      #pragma unroll
      for (int mf = 0; mf < 4; mf++)
        #pragma unroll
        for (int nf = 0; nf < 4; nf++)
          acc[mf][nf] = __builtin_amdgcn_mfma_f32_16x16x32_fp8_fp8(af[mf], bf[nf], acc[mf][nf], 0, 0, 0);
    }
    __syncthreads();
  }

  const float isc = 1.f / 512.f;
  float bv[4];
  #pragma unroll
  for (int nf = 0; nf < 4; nf++) bv[nf] = bias[wn * 64 + nf * 16 + lr];

  #pragma unroll
  for (int mf = 0; mf < 4; mf++) {
    #pragma unroll
    for (int r = 0; r < 4; r++) {
      int grow = m0 + wm * 64 + mf * 16 + lk * 4 + r;
      float s = 0.f, q = 0.f;
      #pragma unroll
      for (int nf = 0; nf < 4; nf++) {
        int col = wn * 64 + nf * 16 + lr;
        float v = acc[mf][nf][r] * isc + bv[nf] + bf2f(res[(size_t)grow * 256 + col]);
        acc[mf][nf][r] = v;
        s += v; q += v * v;
      }
      #pragma unroll
      for (int off = 1; off < 16; off <<= 1) { s += __shfl_xor(s, off); q += __shfl_xor(q, off); }
      if (lr == 0) {
        int lrow = wm * 64 + mf * 16 + lk * 4 + r;
        stats[lrow * 4 + wn] = s;
        stats[512 + lrow * 4 + wn] = q;
      }
    }
  }
  __syncthreads();

  float gv[4], bbv[4];
  #pragma unroll
  for (int nf = 0; nf < 4; nf++) {
    int col = wn * 64 + nf * 16 + lr;
    gv[nf] = g[col]; bbv[nf] = bta[col];
  }
  #pragma unroll
  for (int mf = 0; mf < 4; mf++) {
    #pragma unroll
    for (int r = 0; r < 4; r++) {
      int lrow = wm * 64 + mf * 16 + lk * 4 + r;
      int grow = m0 + lrow;
      float s4 = stats[lrow * 4 + 0] + stats[lrow * 4 + 1] + stats[lrow * 4 + 2] + stats[lrow * 4 + 3];
      float q4 = stats[512 + lrow * 4 + 0] + stats[512 + lrow * 4 + 1]
               + stats[512 + lrow * 4 + 2] + stats[512 + lrow * 4 + 3];
      float mean = s4 * (1.f / 256.f);
      float var = q4 * (1.f / 256.f) - mean * mean;
      float rs = rsqrtf(var + 1e-5f);
      #pragma unroll
      for (int nf = 0; nf < 4; nf++) {
        int col = wn * 64 + nf * 16 + lr;
        float val = (acc[mf][nf][r] - mean) * rs * gv[nf] + bbv[nf];
        xb[(size_t)grow * 256 + col] = f2bf(val);
        if (WR32) x32[(size_t)grow * 256 + col] = val;
      }
    }
  }
}

// ------------- attention: fp8 qkv in, fp8 MFMA, bf16 ob out -------------
// Scales: q,k,v fp8 x32; S_fp8 = S*1024 -> softmax scale /1024 (shift-inv);
// P fp8 x128; O_acc = O*4096 -> ob = acc/4096. LDS 7 KB (byte arrays,
// stride-72 rows for vt/ps -> 18-bank spread). Staging linear-dest.
__global__ __launch_bounds__(64) void attn_kernel(const unsigned char* __restrict__ qkv,
                                                  unsigned short* __restrict__ ob) {
  __shared__ unsigned char al[7168];
  unsigned char* qs = al;              // [64][32] B [0,2048)
  unsigned char* ks = al + 2048;       // [2048,4096)
  unsigned char* vs = al + 4096;       // [4096,6144)
  unsigned char* vt = al;              // [32][72] B [0,2304)   (aliases qs+ks head)
  unsigned char* ps = al + 2304;       // [64][72] B [2304,6912) (aliases rest)
  const int bh = blockIdx.x;
  const int b = bh >> 3, h = bh & 7;
  const int lane = threadIdx.x;
  const int lr = lane & 15, lk = lane >> 4;

  #pragma unroll
  for (int p = 0; p < 2; p++) {
    int u = lane + p * 64;           // u in [0,128): row u>>1, 16B seg u&1
    int row = u >> 1, seg = u & 1;
    size_t gb = (size_t)(b * 64 + row) * 768 + h * 32 + seg * 16;
    GLOAD_LDS16(qkv + gb, (char*)al + u * 16);
    GLOAD_LDS16(qkv + gb + 256, (char*)al + 2048 + u * 16);
    GLOAD_LDS16(qkv + gb + 512, (char*)al + 4096 + u * 16);
  }
  __syncthreads();

  // Q/K fragments + V row-chunks into registers (before aliased overwrites)
  long long aq[4], bk[4], vchunk[4];
  #pragma unroll
  for (int mi = 0; mi < 4; mi++)
    aq[mi] = *(const long long*)&qs[(mi * 16 + lr) * 32 + lk * 8];
  #pragma unroll
  for (int nj = 0; nj < 4; nj++)
    bk[nj] = *(const long long*)&ks[(nj * 16 + lr) * 32 + lk * 8];
  const int vrow = lane >> 2, vcs = (lane & 3) * 8;
  #pragma unroll
  for (int q = 0; q < 4; q++)
    vchunk[q] = *(const long long*)&vs[(q * 16 + vrow) * 32 + vcs];
  WAITLGKM0();

  // vt[c][k] = V[k][c]
  #pragma unroll
  for (int q = 0; q < 4; q++) {
    unsigned long long vv = (unsigned long long)vchunk[q];
    #pragma unroll
    for (int j = 0; j < 8; j++)
      vt[(vcs + j) * 72 + q * 16 + vrow] = (unsigned char)(vv >> (8 * j));
  }

  // QK^T via fp8 MFMA
  f32x4 s[4][4];
  #pragma unroll
  for (int i = 0; i < 4; i++)
    #pragma unroll
    for (int j = 0; j < 4; j++) s[i][j] = (f32x4)(0.f);
  #pragma unroll
  for (int mi = 0; mi < 4; mi++)
    #pragma unroll
    for (int nj = 0; nj < 4; nj++)
      s[mi][nj] = __builtin_amdgcn_mfma_f32_16x16x32_fp8_fp8(aq[mi], bk[nj], s[mi][nj], 0, 0, 0);

  const float scale = 0.17677669529663687f / 1024.f;   // 1/sqrt(32) / (32*32)
  #pragma unroll
  for (int mi = 0; mi < 4; mi++) {
    #pragma unroll
    for (int r = 0; r < 4; r++) {
      float t0 = s[mi][0][r] * scale, t1 = s[mi][1][r] * scale;
      float t2 = s[mi][2][r] * scale, t3 = s[mi][3][r] * scale;
      float mx = fmaxf(fmaxf(t0, t1), fmaxf(t2, t3));
      #pragma unroll
      for (int off = 8; off; off >>= 1) mx = fmaxf(mx, __shfl_xor(mx, off, 16));
      float e0 = expf(t0 - mx), e1 = expf(t1 - mx), e2 = expf(t2 - mx), e3 = expf(t3 - mx);
      float sm = e0 + e1 + e2 + e3;
      #pragma unroll
      for (int off = 8; off; off >>= 1) sm += __shfl_xor(sm, off, 16);
      float inv = 128.f / sm;                  // fold P x128 scale
      int prow = mi * 16 + lk * 4 + r;
      ps[prow * 72 + lr + 0]  = p2fp8(e0 * inv);
      ps[prow * 72 + lr + 16] = p2fp8(e1 * inv);
      ps[prow * 72 + lr + 32] = p2fp8(e2 * inv);
      ps[prow * 72 + lr + 48] = p2fp8(e3 * inv);
    }
  }
  WAITLGKM0();

  // PV via fp8 MFMA
  f32x4 oacc[4][2];
  #pragma unroll
  for (int i = 0; i < 4; i++) { oacc[i][0] = (f32x4)(0.f); oacc[i][1] = (f32x4)(0.f); }
  #pragma unroll
  for (int kk = 0; kk < 2; kk++) {
    long long bv[2];
    #pragma unroll
    for (int nf = 0; nf < 2; nf++)
      bv[nf] = *(const long long*)&vt[(nf * 16 + lr) * 72 + kk * 32 + lk * 8];
    #pragma unroll
    for (int mi = 0; mi < 4; mi++) {
      long long ap = *(const long long*)&ps[(mi * 16 + lr) * 72 + kk * 32 + lk * 8];
      #pragma unroll
      for (int nf = 0; nf < 2; nf++)
        oacc[mi][nf] = __builtin_amdgcn_mfma_f32_16x16x32_fp8_fp8(ap, bv[nf], oacc[mi][nf], 0, 0, 0);
    }
  }
  const float osc = 1.f / 4096.f;   // undo P x128 and V x32
  #pragma unroll
  for (int mi = 0; mi < 4; mi++)
    #pragma unroll
    for (int nf = 0; nf < 2; nf++)
      #pragma unroll
      for (int r = 0; r < 4; r++) {
        int tok = mi * 16 + lk * 4 + r;
        int c = nf * 16 + lr;
        ob[(size_t)(b * 64 + tok) * 256 + h * 32 + c] = f2bf(oacc[mi][nf][r] * osc);
      }
}

// -------- cluster probs -> log_emit via MFMA (R12-proven, unchanged) --------
__global__ __launch_bounds__(256) void cluster_kernel(const unsigned short* __restrict__ xb,
                                                      const unsigned short* __restrict__ mtb,
                                                      const float* __restrict__ mtn,
                                                      float* __restrict__ log_emit) {
  __shared__ unsigned short ms[32 * 264];   // 16.5 KB
  const int t = threadIdx.x;
  for (int i = t; i < 2112; i += 256)
    ((uint2*)ms)[i] = ((const uint2*)mtb)[i];
  const int lane = t & 63, w = t >> 6;
  const int lr = lane & 15, lk = lane >> 4;
  const float mtn0 = mtn[lr], mtn1 = mtn[16 + lr];
  __syncthreads();

  const size_t tok0 = (size_t)blockIdx.x * 256 + (size_t)w * 64;
  f32x4 s[4][2];
  #pragma unroll
  for (int i = 0; i < 4; i++) { s[i][0] = (f32x4)(0.f); s[i][1] = (f32x4)(0.f); }

  #pragma unroll
  for (int kk = 0; kk < 8; kk++) {
    s16x8 bf0 = *(const s16x8*)&ms[lr * 264 + lk * 8 + kk * 32];
    s16x8 bf1 = *(const s16x8*)&ms[(16 + lr) * 264 + lk * 8 + kk * 32];
    #pragma unroll
    for (int mi = 0; mi < 4; mi++) {
      s16x8 af = *(const s16x8*)&xb[(tok0 + mi * 16 + lr) * 256 + lk * 8 + kk * 32];
      s[mi][0] = __builtin_amdgcn_mfma_f32_16x16x32_bf16(af, bf0, s[mi][0], 0, 0, 0);
      s[mi][1] = __builtin_amdgcn_mfma_f32_16x16x32_bf16(af, bf1, s[mi][1], 0, 0, 0);
    }
  }

  #pragma unroll
  for (int mi = 0; mi < 4; mi++) {
    #pragma unroll
    for (int r = 0; r < 4; r++) {
      float l0 = (2.f * s[mi][0][r] - mtn0) * 0.1f;
      float l1 = (2.f * s[mi][1][r] - mtn1) * 0.1f;
      float mx = fmaxf(l0, l1);
      #pragma unroll
      for (int off = 8; off; off >>= 1) mx = fmaxf(mx, __shfl_xor(mx, off, 16));
      float e0 = expf(l0 - mx), e1 = expf(l1 - mx);
      float sm = e0 + e1;
      #pragma unroll
      for (int off = 8; off; off >>= 1) sm += __shfl_xor(sm, off, 16);
      float inv = 1.f / sm;
      size_t row = tok0 + mi * 16 + lk * 4 + r;
      log_emit[row * 32 + lr]      = logf(e0 * inv + 1e-10f);
      log_emit[row * 32 + 16 + lr] = logf(e1 * inv + 1e-10f);
    }
  }
}

// ---------------- HMM forward scan + entropy ----------------
__global__ __launch_bounds__(256) void scan_kernel(const float* __restrict__ log_emit,
                                                   const float* __restrict__ pi,
                                                   const float* __restrict__ A,
                                                   float* __restrict__ cp,
                                                   float* __restrict__ ent) {
  const int g = threadIdx.x >> 5, j = threadIdx.x & 31;
  const int batch = blockIdx.x * 8 + g;
  float regA[32];
  #pragma unroll
  for (int i = 0; i < 32; i++) regA[i] = A[i * 32 + j];
  const float* le = log_emit + (size_t)batch * 64 * 32;
  float* cpo = cp + (size_t)batch * 64 * 32;

  float u = logf(pi[j] + 1e-10f) + le[j];
  float mx = u;
  #pragma unroll
  for (int off = 16; off; off >>= 1) mx = fmaxf(mx, __shfl_xor(mx, off, 32));
  float e = expf(u - mx), sm = e;
  #pragma unroll
  for (int off = 16; off; off >>= 1) sm += __shfl_xor(sm, off, 32);
  float p = e / sm;
  cpo[j] = p;
  float enta = p * logf(p + 1e-10f);

  for (int n = 1; n < 64; n++) {
    float tt = 0.f;
    #pragma unroll
    for (int i = 0; i < 32; i++) tt += __shfl(p, i, 32) * regA[i];
    u = logf(tt + 1e-10f) + le[n * 32 + j];
    mx = u;
    #pragma unroll
    for (int off = 16; off; off >>= 1) mx = fmaxf(mx, __shfl_xor(mx, off, 32));
    e = expf(u - mx); sm = e;
    #pragma unroll
    for (int off = 16; off; off >>= 1) sm += __shfl_xor(sm, off, 32);
    p = e / sm;
    cpo[n * 32 + j] = p;
    enta += p * logf(p + 1e-10f);
  }
  #pragma unroll
  for (int off = 16; off; off >>= 1) enta += __shfl_xor(enta, off, 32);
  if (j == 0) atomicAdd(ent, -enta * (1.f / (2048.f * 64.f)));
}

// ---------------- launcher ----------------
extern "C" void kernel_launch(void* const* d_in, const int* in_sizes, int n_in,
                              void* d_out, int out_size, void* d_ws, size_t ws_size,
                              hipStream_t stream) {
  const float* input = (const float*)d_in[0];
  const float* init_logits = (const float*)d_in[1];
  const float* trans = (const float*)d_in[2];
  const float* Wqkv = (const float*)d_in[3];
  const float* bqkv = (const float*)d_in[4];
  const float* Wo = (const float*)d_in[5];
  const float* bo = (const float*)d_in[6];
  const float* ln1g = (const float*)d_in[7];
  const float* ln1b = (const float*)d_in[8];
  const float* ln2g = (const float*)d_in[9];
  const float* ln2b = (const float*)d_in[10];
  const float* W1 = (const float*)d_in[11];
  const float* b1 = (const float*)d_in[12];
  const float* W2 = (const float*)d_in[13];
  const float* b2 = (const float*)d_in[14];
  const float* mus = (const float*)d_in[15];

  float* out = (float*)d_out;
  float* cp = out;                  // [BN,32]
  float* x = out + 4194304;         // emb_all [BN,256] f32
  float* d_pi = out + 37748736;
  float* d_A = out + 37748768;
  float* d_ent = out + 37749792;

  char* ws = (char*)d_ws;
  unsigned char* qkv = (unsigned char*)ws;          // region A: qkv fp8 96MB -> hb fp8 128MB -> log_emit
  unsigned char* hb = (unsigned char*)ws;
  float* log_emit = (float*)ws;
  unsigned short* ob = (unsigned short*)(ws + 268435456ull);   // region B: attn out bf16
  unsigned short* xb = (unsigned short*)(ws + 335544320ull);   // residual stream bf16
  unsigned short* wq_b = (unsigned short*)(ws + 402653184ull);
  unsigned short* wo_b = (unsigned short*)(ws + 402653184ull + 786432ull);
  unsigned short* w1_b = (unsigned short*)(ws + 402653184ull + 1048576ull);
  unsigned char* w2_f = (unsigned char*)(ws + 402653184ull + 2097152ull);   // fp8 x64
  unsigned short* mtb = (unsigned short*)(ws + 402653184ull + 3145728ull);
  float* mtn = (float*)(ws + 402653184ull + 3178496ull);

  cvt_kernel<<<2048, 256, 0, stream>>>((const float4*)input, (ushort4*)xb, BNT * 256 / 4);
  cvtw_kernel<<<512, 256, 0, stream>>>((const float4*)Wqkv, (ushort4*)wq_b,
                                       (const float4*)Wo, (ushort4*)wo_b,
                                       (const float4*)W1, (ushort4*)w1_b,
                                       (const float4*)W2, (uchar4*)w2_f);
  mtpi_kernel<<<2, 64, 0, stream>>>(mus, mtb, mtn, init_logits, trans, d_pi, d_A, d_ent);

  for (int l = 0; l < 2; l++) {
    // QKV: bf16 x bf16 -> fp8 (x32) out
    gemm_nt<2><<<6144, 256, 0, stream>>>(xb, wq_b + l * 196608, bqkv + l * 768,
                                         qkv, 768, 256, 6);
    attn_kernel<<<16384, 64, 0, stream>>>(qkv, ob);
    gemm_ln<false><<<1024, 512, 0, stream>>>(ob, wo_b + l * 65536, bo + l * 256,
                                             xb, ln1g + l * 256, ln1b + l * 256,
                                             xb, nullptr, 256);
    gemm_nt<1><<<8192, 256, 0, stream>>>(xb, w1_b + l * 262144, b1 + l * 1024,
                                         hb, 1024, 256, 8);
    if (l == LLN - 1)
      gemm_ln_fp8<true><<<1024, 512, 0, stream>>>(hb, w2_f + l * 262144, b2 + l * 256,
                                                  xb, ln2g + l * 256, ln2b + l * 256,
                                                  xb, x, 1024);
    else
      gemm_ln_fp8<false><<<1024, 512, 0, stream>>>(hb, w2_f + l * 262144, b2 + l * 256,
                                                   xb, ln2g + l * 256, ln2b + l * 256,
                                                   xb, nullptr, 1024);
  }

  cluster_kernel<<<512, 256, 0, stream>>>(xb, mtb, mtn, log_emit);
  scan_kernel<<<256, 256, 0, stream>>>(log_emit, d_pi, d_A, cp, d_ent);
}

// Round 18
// 1059.051 us; speedup vs baseline: 1.0643x; 1.0154x over previous
//
#include <hip/hip_runtime.h>

#define BB   2048
#define NNX  64
#define DD   256
#define KKC  32
#define LLN  2
#define HHN  8
#define DHH  32
#define DFFN 1024
#define BNT  (BB*NNX)   // 131072

typedef short s16x8 __attribute__((ext_vector_type(8)));
typedef float f32x4 __attribute__((ext_vector_type(4)));

#define GLOAD_LDS16(gp, lp) __builtin_amdgcn_global_load_lds( \
    (const __attribute__((address_space(1))) void*)(gp),      \
    (__attribute__((address_space(3))) void*)(lp), 16, 0, 0)

#define WAITVM4() asm volatile("s_waitcnt vmcnt(4)" ::: "memory")
#define WAITVM0() asm volatile("s_waitcnt vmcnt(0)" ::: "memory")
#define WAITLGKM0() do { asm volatile("s_waitcnt lgkmcnt(0)" ::: "memory"); \
                         __builtin_amdgcn_sched_barrier(0); } while (0)
#define SBAR() __builtin_amdgcn_s_barrier()

__device__ __forceinline__ unsigned short f2bf(float f) {
  unsigned int u = __float_as_uint(f);
  u += 0x7fffu + ((u >> 16) & 1u);   // RNE
  return (unsigned short)(u >> 16);
}
__device__ __forceinline__ float bf2f(unsigned short u) {
  return __uint_as_float(((unsigned int)u) << 16);
}

// f32 -> fp8 e4m3fn (OCP), input must be >= 0 and <= 448
__device__ __forceinline__ unsigned char f2fp8(float f) {
  unsigned u = __float_as_uint(f);
  unsigned lsb = (u >> 20) & 1u;
  u += 0x7FFFFu + lsb;                 // RNE at mantissa bit 20
  int e = (int)((u >> 23) & 255u) - 120;
  if (e <= 0) {                        // subnormal: units of 2^-9
    int q = (int)(f * 512.f + 0.5f);   // q in [0,8]; 8 rolls into first normal
    return (unsigned char)q;
  }
  if (e > 15) return 0x7E;             // clamp to 448
  return (unsigned char)((e << 3) | ((u >> 20) & 7u));
}
__device__ __forceinline__ unsigned char f2fp8s(float f) {  // signed
  unsigned s = __float_as_uint(f) >> 31;
  float a = fminf(fabsf(f), 448.f);
  return (unsigned char)((s << 7) | f2fp8(a));
}
// cheap unsigned fp8 (flush tiny to 0) for softmax probabilities
__device__ __forceinline__ unsigned char p2fp8(float f) {
  unsigned u = __float_as_uint(f);
  u += 0x7FFFFu + ((u >> 20) & 1u);
  int e = (int)((u >> 23) & 255u) - 120;
  if (e <= 0) return 0;
  return (unsigned char)((e << 3) | ((u >> 20) & 7u));
}

// ---------------- f32 -> bf16 bulk convert (input) ----------------
__global__ __launch_bounds__(256) void cvt_kernel(const float4* __restrict__ src,
                                                  ushort4* __restrict__ dst, int n4) {
  int i = blockIdx.x * 256 + threadIdx.x;
  int st = gridDim.x * 256;
  for (; i < n4; i += st) {
    float4 v = src[i];
    ushort4 o;
    o.x = f2bf(v.x); o.y = f2bf(v.y); o.z = f2bf(v.z); o.w = f2bf(v.w);
    dst[i] = o;
  }
}

// ---- weights convert + setup tables, one launch ----
// blocks [0,512): wq/wo/w1 -> bf16, w2 -> fp8 (x64) grid-stride
// block 512: tanh(mu) table; block 513: pi/A softmax + ent zero
__global__ __launch_bounds__(256) void cvtw_kernel(const float4* __restrict__ wq, ushort4* __restrict__ dq,
                                                   const float4* __restrict__ wo, ushort4* __restrict__ dov,
                                                   const float4* __restrict__ w1, ushort4* __restrict__ d1,
                                                   const float4* __restrict__ w2, uchar4* __restrict__ d2,
                                                   const float* __restrict__ mus, unsigned short* __restrict__ mtb,
                                                   float* __restrict__ mtn,
                                                   const float* __restrict__ il, const float* __restrict__ tl,
                                                   float* __restrict__ d_pi, float* __restrict__ d_A,
                                                   float* __restrict__ d_ent) {
  if (blockIdx.x >= 512) {
    int lane = threadIdx.x;
    if (blockIdx.x == 512) {
      if (lane < 32) {
        float acc = 0.f;
        for (int d = 0; d < 256; d++) {
          float t = tanhf(mus[lane * 256 + d]);
          mtb[lane * 264 + d] = f2bf(t);
          acc += t * t;
        }
        mtn[lane] = acc;
      }
    } else {
      if (lane == 0) *d_ent = 0.f;
      if (lane < 32) {
        float v = il[lane];
        float mx = v;
        #pragma unroll
        for (int off = 16; off; off >>= 1) mx = fmaxf(mx, __shfl_xor(mx, off, 32));
        float e = expf(v - mx), sm = e;
        #pragma unroll
        for (int off = 16; off; off >>= 1) sm += __shfl_xor(sm, off, 32);
        d_pi[lane] = e / sm;
        for (int r = 0; r < 32; r++) {
          float a = tl[r * 32 + lane];
          float m2 = a;
          #pragma unroll
          for (int off = 16; off; off >>= 1) m2 = fmaxf(m2, __shfl_xor(m2, off, 32));
          float e2 = expf(a - m2), s2 = e2;
          #pragma unroll
          for (int off = 16; off; off >>= 1) s2 += __shfl_xor(s2, off, 32);
          d_A[r * 32 + lane] = e2 / s2;
        }
      }
    }
    return;
  }
  const int n0 = 98304, n1 = 32768, n2 = 131072, n3 = 131072;  // float4 counts
  int i = blockIdx.x * 256 + threadIdx.x;
  int st = 512 * 256;
  for (; i < n0 + n1 + n2 + n3; i += st) {
    int j = i;
    if (j < n0) {
      float4 v = wq[j];
      dq[j] = (ushort4){f2bf(v.x), f2bf(v.y), f2bf(v.z), f2bf(v.w)};
    } else if ((j -= n0) < n1) {
      float4 v = wo[j];
      dov[j] = (ushort4){f2bf(v.x), f2bf(v.y), f2bf(v.z), f2bf(v.w)};
    } else if ((j -= n1) < n2) {
      float4 v = w1[j];
      d1[j] = (ushort4){f2bf(v.x), f2bf(v.y), f2bf(v.z), f2bf(v.w)};
    } else {
      j -= n2;
      float4 v = w2[j];
      d2[j] = (uchar4){f2fp8s(v.x * 64.f), f2fp8s(v.y * 64.f),
                       f2fp8s(v.z * 64.f), f2fp8s(v.w * 64.f)};
    }
  }
}

// ======== 128x128 tile, BK=32, 4-wave, counted-vmcnt pipelined NT GEMM ========
// EPI 0: bf16 out; 1: relu -> fp8 (x8); 2: fp8 signed (x32, for qkv).
template <int EPI>
__global__ __launch_bounds__(256, 4) void gemm_nt(const unsigned short* __restrict__ A,
                                                  const unsigned short* __restrict__ Bw,
                                                  const float* __restrict__ bias,
                                                  void* __restrict__ outp,
                                                  int N, int K, int nx) {
  __shared__ unsigned short lds[16384];   // 32 KB: [2 buf][A 4096 | B 4096]
  const int t = threadIdx.x;
  const int bid = blockIdx.x, nwg = gridDim.x;
  const int wg = (bid & 7) * (nwg >> 3) + (bid >> 3);   // nwg % 8 == 0
  const int m0 = (wg / nx) << 7;
  const int n0 = (wg % nx) << 7;
  const int lane = t & 63, w = t >> 6;
  const int wm = w >> 1, wn = w & 1;      // 2x2 waves, wave tile 64x64
  const int lr = lane & 15, lk = lane >> 4;

  const int r0 = t >> 2, sg = t & 3;
  const int s0 = sg ^ ((r0 >> 1) & 3);
  const int r1 = r0 + 64;
  const int s1 = sg ^ ((r1 >> 1) & 3);
  const int aoff0 = (m0 + r0) * K + s0 * 8;
  const int aoff1 = (m0 + r1) * K + s1 * 8;
  const int boff0 = (n0 + r0) * K + s0 * 8;
  const int boff1 = (n0 + r1) * K + s1 * 8;

#define STAGE(buf, k0) do {                                    \
    char* la = (char*)lds + (buf) * 16384;                     \
    GLOAD_LDS16(A + aoff0 + (k0), la + t * 16);                \
    GLOAD_LDS16(A + aoff1 + (k0), la + 4096 + t * 16);         \
    GLOAD_LDS16(Bw + boff0 + (k0), la + 8192 + t * 16);        \
    GLOAD_LDS16(Bw + boff1 + (k0), la + 12288 + t * 16);       \
  } while (0)

  f32x4 acc[4][4];
  #pragma unroll
  for (int i = 0; i < 4; i++)
    #pragma unroll
    for (int j = 0; j < 4; j++) acc[i][j] = (f32x4)(0.f);

  const int ra = wm * 64 + lr, rb = wn * 64 + lr;
  const int sla = lk ^ ((ra >> 1) & 3), slb = lk ^ ((rb >> 1) & 3);

  const int NT = K >> 5;
  STAGE(0, 0);
  STAGE(1, 32);
  WAITVM4();
  SBAR();

  int c = 0;
  for (int kt = 0; kt < NT; kt++) {
    s16x8 af[4], bf[4];
    {
      const unsigned short* ua = lds + c * 8192;
      const unsigned short* ub = ua + 4096;
      #pragma unroll
      for (int mf = 0; mf < 4; mf++)
        af[mf] = *(const s16x8*)&ua[(ra + mf * 16) * 32 + sla * 8];
      #pragma unroll
      for (int nf = 0; nf < 4; nf++)
        bf[nf] = *(const s16x8*)&ub[(rb + nf * 16) * 32 + slb * 8];
    }
    __builtin_amdgcn_s_setprio(1);
    #pragma unroll
    for (int mf = 0; mf < 4; mf++)
      #pragma unroll
      for (int nf = 0; nf < 4; nf++)
        acc[mf][nf] = __builtin_amdgcn_mfma_f32_16x16x32_bf16(af[mf], bf[nf], acc[mf][nf], 0, 0, 0);
    __builtin_amdgcn_s_setprio(0);
    SBAR();
    if (kt < NT - 2) {
      STAGE(c, (kt + 2) << 5);
      WAITVM4();
    } else if (kt == NT - 2) {
      WAITVM0();
    }
    SBAR();
    c ^= 1;
  }
#undef STAGE

  #pragma unroll
  for (int nf = 0; nf < 4; nf++) {
    int col = n0 + wn * 64 + nf * 16 + lr;
    float bv = bias[col];
    #pragma unroll
    for (int mf = 0; mf < 4; mf++)
      #pragma unroll
      for (int r = 0; r < 4; r++) {
        int row = m0 + wm * 64 + mf * 16 + lk * 4 + r;
        size_t o = (size_t)row * N + col;
        float v = acc[mf][nf][r] + bv;
        if (EPI == 0) {
          ((unsigned short*)outp)[o] = f2bf(v);
        } else if (EPI == 1) {
          float hh = fminf(fmaxf(v, 0.f) * 8.f, 448.f);
          ((unsigned char*)outp)[o] = f2fp8(hh);
        } else {
          ((unsigned char*)outp)[o] = f2fp8s(v * 32.f);
        }
      }
  }
}

// ------- GEMM (BM=128, BN=256 full width) + bias + residual + LayerNorm -------
// (R4-measured bf16 version; used for the Wo projection, K=256)
template <bool WR32>
__global__ __launch_bounds__(512) void gemm_ln(const unsigned short* __restrict__ A,
                                               const unsigned short* __restrict__ Bw,
                                               const float* __restrict__ bias,
                                               const unsigned short* __restrict__ res,
                                               const float* __restrict__ g,
                                               const float* __restrict__ bta,
                                               unsigned short* __restrict__ xb,
                                               float* __restrict__ x32,
                                               int K) {
  __shared__ unsigned short As[128 * 64];
  __shared__ unsigned short Bs[256 * 64];
  __shared__ float stats[2][128][4];
  const int t = threadIdx.x;
  const int nwg = gridDim.x;
  const int bid = blockIdx.x;
  const int wg = (bid & 7) * (nwg >> 3) + (bid >> 3);
  const int m0 = wg << 7;

  const int lane = t & 63, w = t >> 6;
  const int wm = w >> 2, wn = w & 3;
  const int lr = lane & 15, lk = lane >> 4;

  size_t aoff[2], boff[4];
  #pragma unroll
  for (int p = 0; p < 2; p++) {
    int u = p * 512 + t;
    int row = u >> 3, sp = u & 7;
    int seg = sp ^ (((row >> 2) & 1) << 1);
    aoff[p] = (size_t)(m0 + row) * K + seg * 8;
  }
  #pragma unroll
  for (int p = 0; p < 4; p++) {
    int u = p * 512 + t;
    int row = u >> 3, sp = u & 7;
    int seg = sp ^ (((row >> 2) & 1) << 1);
    boff[p] = (size_t)row * K + seg * 8;
  }

  f32x4 acc[4][4];
  #pragma unroll
  for (int i = 0; i < 4; i++)
    #pragma unroll
    for (int j = 0; j < 4; j++) acc[i][j] = (f32x4)(0.f);

  for (int k0 = 0; k0 < K; k0 += 64) {
    #pragma unroll
    for (int p = 0; p < 2; p++)
      GLOAD_LDS16(A + aoff[p] + k0, (char*)As + (p * 512 + t) * 16);
    #pragma unroll
    for (int p = 0; p < 4; p++)
      GLOAD_LDS16(Bw + boff[p] + k0, (char*)Bs + (p * 512 + t) * 16);
    __syncthreads();
    #pragma unroll
    for (int z = 0; z < 2; z++) {
      s16x8 af[4], bfr[4];
      #pragma unroll
      for (int mf = 0; mf < 4; mf++) {
        int row = wm * 64 + mf * 16 + lr;
        int cc = (z * 4 + lk) ^ (((row >> 2) & 1) << 1);
        af[mf] = *(const s16x8*)&As[row * 64 + cc * 8];
      }
      #pragma unroll
      for (int nf = 0; nf < 4; nf++) {
        int row = wn * 64 + nf * 16 + lr;
        int cc = (z * 4 + lk) ^ (((row >> 2) & 1) << 1);
        bfr[nf] = *(const s16x8*)&Bs[row * 64 + cc * 8];
      }
      #pragma unroll
      for (int mf = 0; mf < 4; mf++)
        #pragma unroll
        for (int nf = 0; nf < 4; nf++)
          acc[mf][nf] = __builtin_amdgcn_mfma_f32_16x16x32_bf16(af[mf], bfr[nf], acc[mf][nf], 0, 0, 0);
    }
    __syncthreads();
  }

  float bv[4];
  #pragma unroll
  for (int nf = 0; nf < 4; nf++) bv[nf] = bias[wn * 64 + nf * 16 + lr];

  #pragma unroll
  for (int mf = 0; mf < 4; mf++) {
    #pragma unroll
    for (int r = 0; r < 4; r++) {
      int grow = m0 + wm * 64 + mf * 16 + lk * 4 + r;
      float s = 0.f, q = 0.f;
      #pragma unroll
      for (int nf = 0; nf < 4; nf++) {
        int col = wn * 64 + nf * 16 + lr;
        float v = acc[mf][nf][r] + bv[nf] + bf2f(res[(size_t)grow * 256 + col]);
        acc[mf][nf][r] = v;
        s += v; q += v * v;
      }
      #pragma unroll
      for (int off = 1; off < 16; off <<= 1) { s += __shfl_xor(s, off); q += __shfl_xor(q, off); }
      if (lr == 0) {
        int lrow = wm * 64 + mf * 16 + lk * 4 + r;
        stats[0][lrow][wn] = s;
        stats[1][lrow][wn] = q;
      }
    }
  }
  __syncthreads();

  float gv[4], bbv[4];
  #pragma unroll
  for (int nf = 0; nf < 4; nf++) {
    int col = wn * 64 + nf * 16 + lr;
    gv[nf] = g[col]; bbv[nf] = bta[col];
  }
  #pragma unroll
  for (int mf = 0; mf < 4; mf++) {
    #pragma unroll
    for (int r = 0; r < 4; r++) {
      int lrow = wm * 64 + mf * 16 + lk * 4 + r;
      int grow = m0 + lrow;
      float s4 = stats[0][lrow][0] + stats[0][lrow][1] + stats[0][lrow][2] + stats[0][lrow][3];
      float q4 = stats[1][lrow][0] + stats[1][lrow][1] + stats[1][lrow][2] + stats[1][lrow][3];
      float mean = s4 * (1.f / 256.f);
      float var = q4 * (1.f / 256.f) - mean * mean;
      float rs = rsqrtf(var + 1e-5f);
      #pragma unroll
      for (int nf = 0; nf < 4; nf++) {
        int col = wn * 64 + nf * 16 + lr;
        float val = (acc[mf][nf][r] - mean) * rs * gv[nf] + bbv[nf];
        xb[(size_t)grow * 256 + col] = f2bf(val);
        if (WR32) x32[(size_t)grow * 256 + col] = val;
      }
    }
  }
}

// ---- fp8 GEMM (BM=128, BN=256 full width) + bias + residual + LayerNorm ----
// (R15-validated; FFN2 only, isc = 1/512)
template <bool WR32>
__global__ __launch_bounds__(512) void gemm_ln_fp8(const unsigned char* __restrict__ A,
                                                   const unsigned char* __restrict__ Bw,
                                                   const float* __restrict__ bias,
                                                   const unsigned short* __restrict__ res,
                                                   const float* __restrict__ g,
                                                   const float* __restrict__ bta,
                                                   unsigned short* __restrict__ xb,
                                                   float* __restrict__ x32,
                                                   int K) {
  __shared__ unsigned char lds8[24576];   // A 8192 B | B 16384 B
  float* stats = (float*)lds8;            // 4 KB, post-loop only
  const int t = threadIdx.x;
  const int nwg = gridDim.x;
  const int bid = blockIdx.x;
  const int wg = (bid & 7) * (nwg >> 3) + (bid >> 3);
  const int m0 = wg << 7;

  const int lane = t & 63, w = t >> 6;
  const int wm = w >> 2, wn = w & 3;
  const int lr = lane & 15, lk = lane >> 4;

  const int auu = t >> 8, arow = (t >> 1) & 127, asg = t & 1;
  const size_t aoff = (size_t)(m0 + arow) * K + auu * 32 + asg * 16;
  size_t boff[2];
  #pragma unroll
  for (int p = 0; p < 2; p++) {
    int idx = p * 512 + t;
    int buu = idx >> 9, brow = (idx >> 1) & 255, bsg = idx & 1;
    boff[p] = (size_t)brow * K + buu * 32 + bsg * 16;
  }

  f32x4 acc[4][4];
  #pragma unroll
  for (int i = 0; i < 4; i++)
    #pragma unroll
    for (int j = 0; j < 4; j++) acc[i][j] = (f32x4)(0.f);

  for (int k0 = 0; k0 < K; k0 += 64) {
    GLOAD_LDS16(A + aoff + k0, (char*)lds8 + t * 16);
    GLOAD_LDS16(Bw + boff[0] + k0, (char*)lds8 + 8192 + t * 16);
    GLOAD_LDS16(Bw + boff[1] + k0, (char*)lds8 + 16384 + t * 16);
    __syncthreads();
    #pragma unroll
    for (int kk = 0; kk < 2; kk++) {
      long long af[4], bf[4];
      #pragma unroll
      for (int mf = 0; mf < 4; mf++)
        af[mf] = *(const long long*)&lds8[kk * 4096 + (wm * 64 + mf * 16 + lr) * 32 + lk * 8];
      #pragma unroll
      for (int nf = 0; nf < 4; nf++)
        bf[nf] = *(const long long*)&lds8[8192 + kk * 8192 + (wn * 64 + nf * 16 + lr) * 32 + lk * 8];
      #pragma unroll
      for (int mf = 0; mf < 4; mf++)
        #pragma unroll
        for (int nf = 0; nf < 4; nf++)
          acc[mf][nf] = __builtin_amdgcn_mfma_f32_16x16x32_fp8_fp8(af[mf], bf[nf], acc[mf][nf], 0, 0, 0);
    }
    __syncthreads();
  }

  const float isc = 1.f / 512.f;
  float bv[4];
  #pragma unroll
  for (int nf = 0; nf < 4; nf++) bv[nf] = bias[wn * 64 + nf * 16 + lr];

  #pragma unroll
  for (int mf = 0; mf < 4; mf++) {
    #pragma unroll
    for (int r = 0; r < 4; r++) {
      int grow = m0 + wm * 64 + mf * 16 + lk * 4 + r;
      float s = 0.f, q = 0.f;
      #pragma unroll
      for (int nf = 0; nf < 4; nf++) {
        int col = wn * 64 + nf * 16 + lr;
        float v = acc[mf][nf][r] * isc + bv[nf] + bf2f(res[(size_t)grow * 256 + col]);
        acc[mf][nf][r] = v;
        s += v; q += v * v;
      }
      #pragma unroll
      for (int off = 1; off < 16; off <<= 1) { s += __shfl_xor(s, off); q += __shfl_xor(q, off); }
      if (lr == 0) {
        int lrow = wm * 64 + mf * 16 + lk * 4 + r;
        stats[lrow * 4 + wn] = s;
        stats[512 + lrow * 4 + wn] = q;
      }
    }
  }
  __syncthreads();

  float gv[4], bbv[4];
  #pragma unroll
  for (int nf = 0; nf < 4; nf++) {
    int col = wn * 64 + nf * 16 + lr;
    gv[nf] = g[col]; bbv[nf] = bta[col];
  }
  #pragma unroll
  for (int mf = 0; mf < 4; mf++) {
    #pragma unroll
    for (int r = 0; r < 4; r++) {
      int lrow = wm * 64 + mf * 16 + lk * 4 + r;
      int grow = m0 + lrow;
      float s4 = stats[lrow * 4 + 0] + stats[lrow * 4 + 1] + stats[lrow * 4 + 2] + stats[lrow * 4 + 3];
      float q4 = stats[512 + lrow * 4 + 0] + stats[512 + lrow * 4 + 1]
               + stats[512 + lrow * 4 + 2] + stats[512 + lrow * 4 + 3];
      float mean = s4 * (1.f / 256.f);
      float var = q4 * (1.f / 256.f) - mean * mean;
      float rs = rsqrtf(var + 1e-5f);
      #pragma unroll
      for (int nf = 0; nf < 4; nf++) {
        int col = wn * 64 + nf * 16 + lr;
        float val = (acc[mf][nf][r] - mean) * rs * gv[nf] + bbv[nf];
        xb[(size_t)grow * 256 + col] = f2bf(val);
        if (WR32) x32[(size_t)grow * 256 + col] = val;
      }
    }
  }
}

// ------------- attention: fp8 qkv, 4 heads per block (1 wave each) -------------
// (R17-proven body; repacked 4 waves/block, per-wave 7168 B LDS slices)
__global__ __launch_bounds__(256) void attn_kernel(const unsigned char* __restrict__ qkv,
                                                   unsigned short* __restrict__ ob) {
  __shared__ unsigned char al[28672];
  const int wv = threadIdx.x >> 6;
  unsigned char* wb = al + wv * 7168;
  unsigned char* qs = wb;              // [64][32] B [0,2048)
  unsigned char* ks = wb + 2048;       // [2048,4096)
  unsigned char* vs = wb + 4096;       // [4096,6144)
  unsigned char* vt = wb;              // [32][72] B [0,2304)
  unsigned char* ps = wb + 2304;       // [64][72] B [2304,6912)
  const int bh = blockIdx.x * 4 + wv;
  const int b = bh >> 3, h = bh & 7;
  const int lane = threadIdx.x & 63;
  const int lr = lane & 15, lk = lane >> 4;

  #pragma unroll
  for (int p = 0; p < 2; p++) {
    int u = lane + p * 64;           // u in [0,128): row u>>1, 16B seg u&1
    int row = u >> 1, seg = u & 1;
    size_t gb = (size_t)(b * 64 + row) * 768 + h * 32 + seg * 16;
    GLOAD_LDS16(qkv + gb, (char*)wb + u * 16);
    GLOAD_LDS16(qkv + gb + 256, (char*)wb + 2048 + u * 16);
    GLOAD_LDS16(qkv + gb + 512, (char*)wb + 4096 + u * 16);
  }
  __syncthreads();

  long long aq[4], bk[4], vchunk[4];
  #pragma unroll
  for (int mi = 0; mi < 4; mi++)
    aq[mi] = *(const long long*)&qs[(mi * 16 + lr) * 32 + lk * 8];
  #pragma unroll
  for (int nj = 0; nj < 4; nj++)
    bk[nj] = *(const long long*)&ks[(nj * 16 + lr) * 32 + lk * 8];
  const int vrow = lane >> 2, vcs = (lane & 3) * 8;
  #pragma unroll
  for (int q = 0; q < 4; q++)
    vchunk[q] = *(const long long*)&vs[(q * 16 + vrow) * 32 + vcs];
  WAITLGKM0();

  #pragma unroll
  for (int q = 0; q < 4; q++) {
    unsigned long long vv = (unsigned long long)vchunk[q];
    #pragma unroll
    for (int j = 0; j < 8; j++)
      vt[(vcs + j) * 72 + q * 16 + vrow] = (unsigned char)(vv >> (8 * j));
  }

  f32x4 s[4][4];
  #pragma unroll
  for (int i = 0; i < 4; i++)
    #pragma unroll
    for (int j = 0; j < 4; j++) s[i][j] = (f32x4)(0.f);
  #pragma unroll
  for (int mi = 0; mi < 4; mi++)
    #pragma unroll
    for (int nj = 0; nj < 4; nj++)
      s[mi][nj] = __builtin_amdgcn_mfma_f32_16x16x32_fp8_fp8(aq[mi], bk[nj], s[mi][nj], 0, 0, 0);

  const float scale = 0.17677669529663687f / 1024.f;   // 1/sqrt(32) / (32*32)
  #pragma unroll
  for (int mi = 0; mi < 4; mi++) {
    #pragma unroll
    for (int r = 0; r < 4; r++) {
      float t0 = s[mi][0][r] * scale, t1 = s[mi][1][r] * scale;
      float t2 = s[mi][2][r] * scale, t3 = s[mi][3][r] * scale;
      float mx = fmaxf(fmaxf(t0, t1), fmaxf(t2, t3));
      #pragma unroll
      for (int off = 8; off; off >>= 1) mx = fmaxf(mx, __shfl_xor(mx, off, 16));
      float e0 = expf(t0 - mx), e1 = expf(t1 - mx), e2 = expf(t2 - mx), e3 = expf(t3 - mx);
      float sm = e0 + e1 + e2 + e3;
      #pragma unroll
      for (int off = 8; off; off >>= 1) sm += __shfl_xor(sm, off, 16);
      float inv = 128.f / sm;                  // fold P x128 scale
      int prow = mi * 16 + lk * 4 + r;
      ps[prow * 72 + lr + 0]  = p2fp8(e0 * inv);
      ps[prow * 72 + lr + 16] = p2fp8(e1 * inv);
      ps[prow * 72 + lr + 32] = p2fp8(e2 * inv);
      ps[prow * 72 + lr + 48] = p2fp8(e3 * inv);
    }
  }
  WAITLGKM0();

  f32x4 oacc[4][2];
  #pragma unroll
  for (int i = 0; i < 4; i++) { oacc[i][0] = (f32x4)(0.f); oacc[i][1] = (f32x4)(0.f); }
  #pragma unroll
  for (int kk = 0; kk < 2; kk++) {
    long long bv[2];
    #pragma unroll
    for (int nf = 0; nf < 2; nf++)
      bv[nf] = *(const long long*)&vt[(nf * 16 + lr) * 72 + kk * 32 + lk * 8];
    #pragma unroll
    for (int mi = 0; mi < 4; mi++) {
      long long ap = *(const long long*)&ps[(mi * 16 + lr) * 72 + kk * 32 + lk * 8];
      #pragma unroll
      for (int nf = 0; nf < 2; nf++)
        oacc[mi][nf] = __builtin_amdgcn_mfma_f32_16x16x32_fp8_fp8(ap, bv[nf], oacc[mi][nf], 0, 0, 0);
    }
  }
  const float osc = 1.f / 4096.f;   // undo P x128 and V x32
  #pragma unroll
  for (int mi = 0; mi < 4; mi++)
    #pragma unroll
    for (int nf = 0; nf < 2; nf++)
      #pragma unroll
      for (int r = 0; r < 4; r++) {
        int tok = mi * 16 + lk * 4 + r;
        int c = nf * 16 + lr;
        ob[(size_t)(b * 64 + tok) * 256 + h * 32 + c] = f2bf(oacc[mi][nf][r] * osc);
      }
}

// ---- cluster probs + HMM scan fused: wave w of block b owns batch b*4+w ----
// log_emit tile kept in LDS (les); scan runs in-wave on lanes 0..31.
__global__ __launch_bounds__(256) void cluster_scan_kernel(const unsigned short* __restrict__ xb,
                                                           const unsigned short* __restrict__ mtb,
                                                           const float* __restrict__ mtn,
                                                           const float* __restrict__ pi,
                                                           const float* __restrict__ Atr,
                                                           float* __restrict__ cp,
                                                           float* __restrict__ ent) {
  __shared__ unsigned short ms[32 * 264];   // 16.5 KB
  __shared__ float les[4][64][32];          // 32 KB
  const int t = threadIdx.x;
  for (int i = t; i < 2112; i += 256)
    ((uint2*)ms)[i] = ((const uint2*)mtb)[i];
  const int lane = t & 63, w = t >> 6;
  const int lr = lane & 15, lk = lane >> 4;
  const float mtn0 = mtn[lr], mtn1 = mtn[16 + lr];
  __syncthreads();

  const size_t tok0 = (size_t)blockIdx.x * 256 + (size_t)w * 64;
  f32x4 s[4][2];
  #pragma unroll
  for (int i = 0; i < 4; i++) { s[i][0] = (f32x4)(0.f); s[i][1] = (f32x4)(0.f); }

  #pragma unroll
  for (int kk = 0; kk < 8; kk++) {
    s16x8 bf0 = *(const s16x8*)&ms[lr * 264 + lk * 8 + kk * 32];
    s16x8 bf1 = *(const s16x8*)&ms[(16 + lr) * 264 + lk * 8 + kk * 32];
    #pragma unroll
    for (int mi = 0; mi < 4; mi++) {
      s16x8 af = *(const s16x8*)&xb[(tok0 + mi * 16 + lr) * 256 + lk * 8 + kk * 32];
      s[mi][0] = __builtin_amdgcn_mfma_f32_16x16x32_bf16(af, bf0, s[mi][0], 0, 0, 0);
      s[mi][1] = __builtin_amdgcn_mfma_f32_16x16x32_bf16(af, bf1, s[mi][1], 0, 0, 0);
    }
  }

  #pragma unroll
  for (int mi = 0; mi < 4; mi++) {
    #pragma unroll
    for (int r = 0; r < 4; r++) {
      float l0 = (2.f * s[mi][0][r] - mtn0) * 0.1f;
      float l1 = (2.f * s[mi][1][r] - mtn1) * 0.1f;
      float mx = fmaxf(l0, l1);
      #pragma unroll
      for (int off = 8; off; off >>= 1) mx = fmaxf(mx, __shfl_xor(mx, off, 16));
      float e0 = expf(l0 - mx), e1 = expf(l1 - mx);
      float sm = e0 + e1;
      #pragma unroll
      for (int off = 8; off; off >>= 1) sm += __shfl_xor(sm, off, 16);
      float inv = 1.f / sm;
      int row = mi * 16 + lk * 4 + r;
      les[w][row][lr]      = logf(e0 * inv + 1e-10f);
      les[w][row][16 + lr] = logf(e1 * inv + 1e-10f);
    }
  }
  // wave-local LDS dependency (compiler inserts waits; no cross-wave sharing)

  if (lane < 32) {
    const int j = lane;
    const int batch = blockIdx.x * 4 + w;
    float regA[32];
    #pragma unroll
    for (int i = 0; i < 32; i++) regA[i] = Atr[i * 32 + j];
    float* cpo = cp + (size_t)batch * 64 * 32;

    float u = logf(pi[j] + 1e-10f) + les[w][0][j];
    float mx = u;
    #pragma unroll
    for (int off = 16; off; off >>= 1) mx = fmaxf(mx, __shfl_xor(mx, off, 32));
    float e = expf(u - mx), sm = e;
    #pragma unroll
    for (int off = 16; off; off >>= 1) sm += __shfl_xor(sm, off, 32);
    float p = e / sm;
    cpo[j] = p;
    float enta = p * logf(p + 1e-10f);

    for (int n = 1; n < 64; n++) {
      float tt = 0.f;
      #pragma unroll
      for (int i = 0; i < 32; i++) tt += __shfl(p, i, 32) * regA[i];
      u = logf(tt + 1e-10f) + les[w][n][j];
      mx = u;
      #pragma unroll
      for (int off = 16; off; off >>= 1) mx = fmaxf(mx, __shfl_xor(mx, off, 32));
      e = expf(u - mx); sm = e;
      #pragma unroll
      for (int off = 16; off; off >>= 1) sm += __shfl_xor(sm, off, 32);
      p = e / sm;
      cpo[n * 32 + j] = p;
      enta += p * logf(p + 1e-10f);
    }
    #pragma unroll
    for (int off = 16; off; off >>= 1) enta += __shfl_xor(enta, off, 32);
    if (j == 0) atomicAdd(ent, -enta * (1.f / (2048.f * 64.f)));
  }
}

// ---------------- launcher ----------------
extern "C" void kernel_launch(void* const* d_in, const int* in_sizes, int n_in,
                              void* d_out, int out_size, void* d_ws, size_t ws_size,
                              hipStream_t stream) {
  const float* input = (const float*)d_in[0];
  const float* init_logits = (const float*)d_in[1];
  const float* trans = (const float*)d_in[2];
  const float* Wqkv = (const float*)d_in[3];
  const float* bqkv = (const float*)d_in[4];
  const float* Wo = (const float*)d_in[5];
  const float* bo = (const float*)d_in[6];
  const float* ln1g = (const float*)d_in[7];
  const float* ln1b = (const float*)d_in[8];
  const float* ln2g = (const float*)d_in[9];
  const float* ln2b = (const float*)d_in[10];
  const float* W1 = (const float*)d_in[11];
  const float* b1 = (const float*)d_in[12];
  const float* W2 = (const float*)d_in[13];
  const float* b2 = (const float*)d_in[14];
  const float* mus = (const float*)d_in[15];

  float* out = (float*)d_out;
  float* cp = out;                  // [BN,32]
  float* x = out + 4194304;         // emb_all [BN,256] f32
  float* d_pi = out + 37748736;
  float* d_A = out + 37748768;
  float* d_ent = out + 37749792;

  char* ws = (char*)d_ws;
  unsigned char* qkv = (unsigned char*)ws;          // region A: qkv fp8 96MB / hb fp8 128MB
  unsigned char* hb = (unsigned char*)ws;
  unsigned short* ob = (unsigned short*)(ws + 268435456ull);   // region B: attn out bf16
  unsigned short* xb = (unsigned short*)(ws + 335544320ull);   // residual stream bf16
  unsigned short* wq_b = (unsigned short*)(ws + 402653184ull);
  unsigned short* wo_b = (unsigned short*)(ws + 402653184ull + 786432ull);
  unsigned short* w1_b = (unsigned short*)(ws + 402653184ull + 1048576ull);
  unsigned char* w2_f = (unsigned char*)(ws + 402653184ull + 2097152ull);   // fp8 x64
  unsigned short* mtb = (unsigned short*)(ws + 402653184ull + 3145728ull);
  float* mtn = (float*)(ws + 402653184ull + 3178496ull);

  cvt_kernel<<<2048, 256, 0, stream>>>((const float4*)input, (ushort4*)xb, BNT * 256 / 4);
  cvtw_kernel<<<514, 256, 0, stream>>>((const float4*)Wqkv, (ushort4*)wq_b,
                                       (const float4*)Wo, (ushort4*)wo_b,
                                       (const float4*)W1, (ushort4*)w1_b,
                                       (const float4*)W2, (uchar4*)w2_f,
                                       mus, mtb, mtn,
                                       init_logits, trans, d_pi, d_A, d_ent);

  for (int l = 0; l < 2; l++) {
    // QKV: bf16 x bf16 -> fp8 (x32) out
    gemm_nt<2><<<6144, 256, 0, stream>>>(xb, wq_b + l * 196608, bqkv + l * 768,
                                         qkv, 768, 256, 6);
    attn_kernel<<<4096, 256, 0, stream>>>(qkv, ob);
    gemm_ln<false><<<1024, 512, 0, stream>>>(ob, wo_b + l * 65536, bo + l * 256,
                                             xb, ln1g + l * 256, ln1b + l * 256,
                                             xb, nullptr, 256);
    gemm_nt<1><<<8192, 256, 0, stream>>>(xb, w1_b + l * 262144, b1 + l * 1024,
                                         hb, 1024, 256, 8);
    if (l == LLN - 1)
      gemm_ln_fp8<true><<<1024, 512, 0, stream>>>(hb, w2_f + l * 262144, b2 + l * 256,
                                                  xb, ln2g + l * 256, ln2b + l * 256,
                                                  xb, x, 1024);
    else
      gemm_ln_fp8<false><<<1024, 512, 0, stream>>>(hb, w2_f + l * 262144, b2 + l * 256,
                                                   xb, ln2g + l * 256, ln2b + l * 256,
                                                   xb, nullptr, 1024);
  }

  cluster_scan_kernel<<<512, 256, 0, stream>>>(xb, mtb, mtn, d_pi, d_A, cp, d_ent);
}